// Round 11
// baseline (1518.436 us; speedup 1.0000x reference)
//
#include <hip/hip_runtime.h>
#include <hip/hip_cooperative_groups.h>

namespace cg = cooperative_groups;

// Problem constants (fixed by the reference)
#define N_NODES   100000
#define N_EDGES   1600000
#define IN_CH     16
#define HID_CH    64
#define OUT_CH    128
#define N_GRAPHS  128

// Capacities. Expected: slots ~2.2K, list1 ~35K, list2 ~2K.
#define CAPS  4096
#define CAP1  65536
#define CAP2  16384

#define BM_WORDS ((N_NODES + 31) / 32)      // 3125 words = 12.5 KB bitmap

#define NBLK 2048                           // 8 blocks/CU x 256 CU (co-resident)
#define SCAN_CHUNK ((N_EDGES + NBLK - 1) / NBLK)   // 782 edges/block

// Shared arena: 4160 ints = 16640 B. Layouts (per phase, barrier-separated):
//  pass1: bm[0..3124] | lbuf at 3136..3917 | scnt at 4156
//  pass2: lbuf at 0..781 | scnt at 4156
//  l1*  : w1s = float[1024] at 0
//  l2   : cent = int[128] at 0
#define SMEM_INTS 4160
#define LBUF1_OFF 3136
#define SCNT_OFF  4156

struct P {
    const float* x; const int* src; const int* dst; const int* ptr;
    const float* W1; const float* b1; const float* W2; const float* b2;
    float* out;
    unsigned int* deg; int* map1; int* slotnode; int* list1; int* list2;
    float* h1; unsigned int* mbm; unsigned int* ndbm; int* cnt;
};

// ---------------- phase device functions ----------------

__device__ void ph_init(const P& p) {
    int i = blockIdx.x * blockDim.x + threadIdx.x;
    int st = gridDim.x * blockDim.x;
    for (int n = i; n < N_NODES; n += st) { p.deg[n] = 0u; p.map1[n] = -1; }
    for (int n = i; n < CAPS * HID_CH; n += st) p.h1[n] = 0.0f;
    for (int n = i; n < N_GRAPHS * OUT_CH; n += st) p.out[n] = p.b2[n & 127];
    for (int n = i; n < BM_WORDS; n += st) { p.mbm[n] = 0u; p.ndbm[n] = 0u; }
    if (i < 8) p.cnt[i] = 0;
}

// Scan 1: central-dst edges -> list2; mark srcs (and centrals, block 0) -2.
// Central bitmap built per-block in LDS from ptr (no global cbm, no extra sync).
__device__ void ph_pass1(const P& p, int* smem) {
    unsigned int* bm = (unsigned int*)smem;
    int* lbuf = smem + LBUF1_OFF;
    int* scnt = smem + SCNT_OFF;
    for (int t = threadIdx.x; t < BM_WORDS; t += blockDim.x) bm[t] = 0u;
    if (threadIdx.x == 0) scnt[0] = 0;
    __syncthreads();
    if (threadIdx.x < N_GRAPHS) {
        int c = p.ptr[threadIdx.x];
        atomicOr(&bm[c >> 5], 1u << (c & 31));
        if (blockIdx.x == 0) {
            p.map1[c] = -2;                     // centrals need h1 slots
            atomicOr(&p.ndbm[c >> 5], 1u << (c & 31));
        }
    }
    __syncthreads();
    int e0 = blockIdx.x * SCAN_CHUNK;
    int e1 = min(e0 + SCAN_CHUNK, N_EDGES);
    for (int e = e0 + (int)threadIdx.x; e < e1; e += blockDim.x) {
        int d = p.dst[e];
        if ((bm[d >> 5] >> (d & 31)) & 1u) {
            p.map1[p.src[e]] = -2;              // benign same-value race
            lbuf[atomicAdd(&scnt[0], 1)] = e;   // LDS atomic; fits by construction
        }
    }
    __syncthreads();
    if (threadIdx.x == 0) scnt[1] = atomicAdd(&p.cnt[2], scnt[0]);
    __syncthreads();
    for (int t = threadIdx.x; t < scnt[0]; t += blockDim.x) {
        int gi = scnt[1] + t;
        if (gi < CAP2) p.list2[gi] = lbuf[t];
    }
}

// Compact marked nodes -> slots (wave-aggregated counter); mbm + ndbm bits.
__device__ void ph_node(const P& p) {
    int lane = threadIdx.x & 63;
    int i = blockIdx.x * blockDim.x + threadIdx.x;
    int st = gridDim.x * blockDim.x;
    for (int n = i; n < N_NODES; n += st) {
        bool need = (p.map1[n] == -2);
        unsigned long long mk = __ballot(need);
        if (mk) {
            int leader = __ffsll((long long)mk) - 1;
            int base = 0;
            if (lane == leader) base = atomicAdd(&p.cnt[0], __popcll(mk));
            base = __shfl(base, leader, 64);
            if (need) {
                int s = base + (int)__popcll(mk & ((1ull << lane) - 1));
                if (s < CAPS) { p.map1[n] = s; p.slotnode[s] = n; }
                else          { p.map1[n] = 0; }    // overflow: clamp, never fault
                atomicOr(&p.mbm[n >> 5], 1u << (n & 31));
                atomicOr(&p.ndbm[n >> 5], 1u << (n & 31));
            }
        }
    }
}

// Scan 2: marked-dst edges -> list1 (LDS buffer); mark srcs as needing degree.
__device__ void ph_pass2(const P& p, int* smem) {
    int* lbuf = smem;
    int* scnt = smem + SCNT_OFF;
    if (threadIdx.x == 0) scnt[0] = 0;
    __syncthreads();
    int e0 = blockIdx.x * SCAN_CHUNK;
    int e1 = min(e0 + SCAN_CHUNK, N_EDGES);
    for (int e = e0 + (int)threadIdx.x; e < e1; e += blockDim.x) {
        int d = p.dst[e];
        if ((p.mbm[d >> 5] >> (d & 31)) & 1u) {
            int s = p.src[e];
            atomicOr(&p.ndbm[s >> 5], 1u << (s & 31));
            lbuf[atomicAdd(&scnt[0], 1)] = e;
        }
    }
    __syncthreads();
    if (threadIdx.x == 0) scnt[1] = atomicAdd(&p.cnt[1], scnt[0]);
    __syncthreads();
    for (int t = threadIdx.x; t < scnt[0]; t += blockDim.x) {
        int gi = scnt[1] + t;
        if (gi < CAP1) p.list1[gi] = lbuf[t];
    }
}

// Scan 3: degree counting only for dst in the needed set (~31% of edges).
__device__ void ph_pass3(const P& p) {
    int i = blockIdx.x * blockDim.x + threadIdx.x;
    int st = gridDim.x * blockDim.x;
    for (int e = i; e < N_EDGES; e += st) {
        int d = p.dst[e];
        if ((p.ndbm[d >> 5] >> (d & 31)) & 1u) atomicAdd(&p.deg[d], 1u);
    }
}

// Layer-1 edge scatter over list1: one wave/edge; lane = hidden channel.
__device__ void ph_l1edge(const P& p, const float* w1s) {
    int lane = threadIdx.x & 63;
    int wid = blockIdx.x * (blockDim.x >> 6) + (threadIdx.x >> 6);
    int nw = gridDim.x * (blockDim.x >> 6);
    int n1 = min(p.cnt[1], CAP1);
    for (int w = wid; w < n1; w += nw) {
        int e = p.list1[w];
        int s = p.src[e];
        int d = p.dst[e];
        int slot = p.map1[d];                   // >= 0 by construction
        float norm = rsqrtf((float)(1u + p.deg[s])) * rsqrtf((float)(1u + p.deg[d]));
        float xv = (lane < IN_CH) ? p.x[s * IN_CH + lane] : 0.0f;
        float t = 0.0f;
#pragma unroll
        for (int c = 0; c < IN_CH; ++c)
            t += __shfl(xv, c, 64) * w1s[c * HID_CH + lane];
        atomicAdd(&p.h1[(size_t)slot * HID_CH + lane], t * norm);
    }
}

// Layer-1 self-loop + bias + ReLU: one wave/slot.
__device__ void ph_l1self(const P& p, const float* w1s) {
    int lane = threadIdx.x & 63;
    int wid = blockIdx.x * (blockDim.x >> 6) + (threadIdx.x >> 6);
    int nw = gridDim.x * (blockDim.x >> 6);
    int nS = min(p.cnt[0], CAPS);
    for (int sl = wid; sl < nS; sl += nw) {
        int n = p.slotnode[sl];
        float xv = (lane < IN_CH) ? p.x[n * IN_CH + lane] : 0.0f;
        float t = 0.0f;
#pragma unroll
        for (int c = 0; c < IN_CH; ++c)
            t += __shfl(xv, c, 64) * w1s[c * HID_CH + lane];
        float r = rsqrtf((float)(1u + p.deg[n]));
        size_t off = (size_t)sl * HID_CH + lane;
        float v = p.h1[off] + t * r * r + p.b1[lane];
        p.h1[off] = v > 0.0f ? v : 0.0f;
    }
}

// Layer-2: listed central-dst edges (ballot row resolution; duplicate rows each
// accumulate) + 128 self-loop items. Atomics go straight into out (bias pre-set).
__device__ void ph_l2(const P& p, const int* cent) {
    int lane = threadIdx.x & 63;
    int c0 = cent[lane];
    int c1v = cent[lane + 64];
    int wid = blockIdx.x * (blockDim.x >> 6) + (threadIdx.x >> 6);
    int nw = gridDim.x * (blockDim.x >> 6);
    int n2 = min(p.cnt[2], CAP2);
    for (int w = wid; w < n2 + N_GRAPHS; w += nw) {
        int s, d, selfrow = -1;
        if (w < n2) {
            int e = p.list2[w];
            s = p.src[e]; d = p.dst[e];
        } else {
            selfrow = w - n2;
            s = cent[selfrow]; d = s;
        }
        int slot = p.map1[s]; if (slot < 0) slot = 0;     // always marked
        float rs = rsqrtf((float)(1u + p.deg[s]));
        float rd = rsqrtf((float)(1u + p.deg[d]));
        float norm = rs * rd;
        const float* hrow = &p.h1[(size_t)slot * HID_CH];
        float a0 = 0.0f, a1 = 0.0f;
#pragma unroll 8
        for (int j = 0; j < HID_CH; ++j) {
            float hv = hrow[j];
            a0 += hv * p.W2[j * OUT_CH + lane];
            a1 += hv * p.W2[j * OUT_CH + lane + 64];
        }
        a0 *= norm; a1 *= norm;
        if (selfrow >= 0) {
            atomicAdd(&p.out[selfrow * OUT_CH + lane], a0);
            atomicAdd(&p.out[selfrow * OUT_CH + lane + 64], a1);
        } else {
            unsigned long long b0 = __ballot(c0 == d);
            unsigned long long b1 = __ballot(c1v == d);
            while (b0) {
                int r = __ffsll((long long)b0) - 1; b0 &= b0 - 1;
                atomicAdd(&p.out[r * OUT_CH + lane], a0);
                atomicAdd(&p.out[r * OUT_CH + lane + 64], a1);
            }
            while (b1) {
                int r = __ffsll((long long)b1) - 1 + 64; b1 &= b1 - 1;
                atomicAdd(&p.out[r * OUT_CH + lane], a0);
                atomicAdd(&p.out[r * OUT_CH + lane + 64], a1);
            }
        }
    }
}

// ---------------- cooperative mega-kernel ----------------

__global__ void __launch_bounds__(256) k_mega(P p) {
    cg::grid_group g = cg::this_grid();
    __shared__ int smem[SMEM_INTS];             // 16.6 KB arena, phase-unioned

    ph_init(p);                         g.sync();
    ph_pass1(p, smem);                  g.sync();
    ph_node(p);                         g.sync();
    ph_pass2(p, smem);                  g.sync();
    ph_pass3(p);                        g.sync();
    float* w1s = (float*)smem;
    for (int t = threadIdx.x; t < IN_CH * HID_CH; t += blockDim.x) w1s[t] = p.W1[t];
    __syncthreads();
    ph_l1edge(p, w1s);                  g.sync();
    ph_l1self(p, w1s);                  g.sync();
    int* cent = smem;
    if (threadIdx.x < 128) cent[threadIdx.x] = p.ptr[threadIdx.x];
    __syncthreads();
    ph_l2(p, cent);
}

// ---------------- standalone fallback kernels ----------------

__global__ void k_init_s(P p) { ph_init(p); }
__global__ void __launch_bounds__(256) k_pass1_s(P p) {
    __shared__ int smem[SMEM_INTS]; ph_pass1(p, smem);
}
__global__ void k_node_s(P p) { ph_node(p); }
__global__ void __launch_bounds__(256) k_pass2_s(P p) {
    __shared__ int smem[SMEM_INTS]; ph_pass2(p, smem);
}
__global__ void k_pass3_s(P p) { ph_pass3(p); }
__global__ void k_l1edge_s(P p) {
    __shared__ float w1s[IN_CH * HID_CH];
    for (int t = threadIdx.x; t < IN_CH * HID_CH; t += blockDim.x) w1s[t] = p.W1[t];
    __syncthreads();
    ph_l1edge(p, w1s);
}
__global__ void k_l1self_s(P p) {
    __shared__ float w1s[IN_CH * HID_CH];
    for (int t = threadIdx.x; t < IN_CH * HID_CH; t += blockDim.x) w1s[t] = p.W1[t];
    __syncthreads();
    ph_l1self(p, w1s);
}
__global__ void k_l2_s(P p) {
    __shared__ int cent[128];
    if (threadIdx.x < 128) cent[threadIdx.x] = p.ptr[threadIdx.x];
    __syncthreads();
    ph_l2(p, cent);
}

// ---------------- launch ----------------

extern "C" void kernel_launch(void* const* d_in, const int* in_sizes, int n_in,
                              void* d_out, int out_size, void* d_ws, size_t ws_size,
                              hipStream_t stream) {
    P p;
    p.x   = (const float*)d_in[0];          // fp32 (validated)
    const int* edge = (const int*)d_in[1];  // int32 (validated)
    p.src = edge;
    p.dst = edge + N_EDGES;
    p.ptr = (const int*)d_in[2];
    p.W1  = (const float*)d_in[3];
    p.b1  = (const float*)d_in[4];
    p.W2  = (const float*)d_in[5];
    p.b2  = (const float*)d_in[6];
    p.out = (float*)d_out;

    // workspace ~2.2 MB
    char* q = (char*)d_ws;
    auto alloc = [&](size_t bytes) {
        char* r = q; q += (bytes + 255) & ~size_t(255); return r;
    };
    p.deg      = (unsigned int*)alloc((size_t)N_NODES * 4);
    p.map1     = (int*)  alloc((size_t)N_NODES * 4);
    p.slotnode = (int*)  alloc((size_t)CAPS * 4);
    p.list1    = (int*)  alloc((size_t)CAP1 * 4);
    p.list2    = (int*)  alloc((size_t)CAP2 * 4);
    p.h1       = (float*)alloc((size_t)CAPS * HID_CH * 4);
    p.mbm      = (unsigned int*)alloc((size_t)BM_WORDS * 4);
    p.ndbm     = (unsigned int*)alloc((size_t)BM_WORDS * 4);
    p.cnt      = (int*)  alloc(256);

    void* args[] = { (void*)&p };
    hipError_t err = hipLaunchCooperativeKernel((const void*)k_mega,
                                                dim3(NBLK), dim3(256),
                                                args, 0, stream);
    if (err != hipSuccess) {
        (void)hipGetLastError();            // clear sticky error, use fallback
        hipLaunchKernelGGL(k_init_s,   dim3(512),  dim3(256), 0, stream, p);
        hipLaunchKernelGGL(k_pass1_s,  dim3(NBLK), dim3(256), 0, stream, p);
        hipLaunchKernelGGL(k_node_s,   dim3(512),  dim3(256), 0, stream, p);
        hipLaunchKernelGGL(k_pass2_s,  dim3(NBLK), dim3(256), 0, stream, p);
        hipLaunchKernelGGL(k_pass3_s,  dim3(1024), dim3(256), 0, stream, p);
        hipLaunchKernelGGL(k_l1edge_s, dim3(512),  dim3(256), 0, stream, p);
        hipLaunchKernelGGL(k_l1self_s, dim3(128),  dim3(256), 0, stream, p);
        hipLaunchKernelGGL(k_l2_s,     dim3(64),   dim3(256), 0, stream, p);
    }
}

// Round 12
// 244.604 us; speedup vs baseline: 6.2077x; 6.2077x over previous
//
#include <hip/hip_runtime.h>

// Problem constants (fixed by the reference)
#define N_NODES   100000
#define N_EDGES   1600000
#define IN_CH     16
#define HID_CH    64
#define OUT_CH    128
#define N_GRAPHS  128

// Capacities. Expected: slots ~2.2K, list1 ~35K, list2 ~2K.
#define CAPS  4096
#define CAP1  65536
#define CAP2  16384

#define BM_WORDS ((N_NODES + 31) / 32)      // 3125 words = 12.5 KB bitmap

#define NBLK   2048                         // 8 blocks/CU x 256 CU, co-resident
#define GROUPS 32
#define GSIZE  (NBLK / GROUPS)              // 64 blocks per barrier leaf
#define SCAN_CHUNK ((N_EDGES + NBLK - 1) / NBLK)   // 782 edges/block

// LDS arena (ints): [0..3124] bitmap | w1s+b1s | cent ; lbuf@3136 ; scnt@4000
#define SMEM_INTS 4224
#define LBUF_OFF  3136
#define SCNT_OFF  4000

// ---- agent-scope (device-coherent, cache-bypassing) accessors ----
__device__ __forceinline__ int aload(const int* p) {
    return __hip_atomic_load(p, __ATOMIC_RELAXED, __HIP_MEMORY_SCOPE_AGENT);
}
__device__ __forceinline__ unsigned auload(const unsigned* p) {
    return __hip_atomic_load(p, __ATOMIC_RELAXED, __HIP_MEMORY_SCOPE_AGENT);
}
__device__ __forceinline__ float afload(const float* p) {
    return __hip_atomic_load(p, __ATOMIC_RELAXED, __HIP_MEMORY_SCOPE_AGENT);
}
__device__ __forceinline__ void astore(int* p, int v) {
    __hip_atomic_store(p, v, __ATOMIC_RELAXED, __HIP_MEMORY_SCOPE_AGENT);
}
__device__ __forceinline__ void afstore(float* p, float v) {
    __hip_atomic_store(p, v, __ATOMIC_RELAXED, __HIP_MEMORY_SCOPE_AGENT);
}

// ---- tree barrier state (monotonic; zeroed by k_prep each launch) ----
struct GBar { int leaf[GROUPS * 16]; int root[16]; int rootrel[16]; int leafrel[GROUPS * 16]; };
#define BAR_INTS ((int)(sizeof(GBar) / 4))

struct P {
    const float* x; const int* src; const int* dst; const int* ptr;
    const float* W1; const float* b1; const float* W2; const float* b2;
    float* out;
    unsigned* deg; int* map1; int* slotnode; int* list1; int* list2;
    float* h1; unsigned* markbm; unsigned* ndbm; int* cnt; GBar* bar;
};

__device__ __forceinline__ void gbar(GBar* b, int k) {
    __syncthreads();
    if (threadIdx.x == 0) {
        int g = blockIdx.x / GSIZE;
        int a = __hip_atomic_fetch_add(&b->leaf[g * 16], 1, __ATOMIC_RELEASE,
                                       __HIP_MEMORY_SCOPE_AGENT);
        if (a == GSIZE * k - 1) {           // last block of this group
            int r = __hip_atomic_fetch_add(&b->root[0], 1, __ATOMIC_RELEASE,
                                           __HIP_MEMORY_SCOPE_AGENT);
            if (r == GROUPS * k - 1) {
                __hip_atomic_store(&b->rootrel[0], k, __ATOMIC_RELEASE,
                                   __HIP_MEMORY_SCOPE_AGENT);
            } else {
                while (__hip_atomic_load(&b->rootrel[0], __ATOMIC_RELAXED,
                                         __HIP_MEMORY_SCOPE_AGENT) < k)
                    __builtin_amdgcn_s_sleep(2);
            }
            __hip_atomic_store(&b->leafrel[g * 16], k, __ATOMIC_RELEASE,
                               __HIP_MEMORY_SCOPE_AGENT);
        } else {
            while (__hip_atomic_load(&b->leafrel[g * 16], __ATOMIC_RELAXED,
                                     __HIP_MEMORY_SCOPE_AGENT) < k)
                __builtin_amdgcn_s_sleep(2);
        }
        (void)__hip_atomic_load(&b->rootrel[0], __ATOMIC_ACQUIRE,
                                __HIP_MEMORY_SCOPE_AGENT);  // one acquire fence
    }
    __syncthreads();
}

// ---------------- phases ----------------

// Phase 1: LDS central bitmap from ptr; scan chunk; central-dst edges -> list2,
// their srcs (and the centrals themselves, via block 0) -> markbm.
__device__ void ph_pass1(const P& p, int* smem) {
    unsigned* cbm = (unsigned*)smem;
    int* lbuf = smem + LBUF_OFF;
    int* scnt = smem + SCNT_OFF;
    for (int t = threadIdx.x; t < BM_WORDS; t += blockDim.x) cbm[t] = 0u;
    if (threadIdx.x == 0) scnt[0] = 0;
    __syncthreads();
    if (threadIdx.x < N_GRAPHS) {
        int c = p.ptr[threadIdx.x];
        atomicOr(&cbm[c >> 5], 1u << (c & 31));
        if (blockIdx.x == 0)
            atomicOr(&p.markbm[c >> 5], 1u << (c & 31));
    }
    __syncthreads();
    int e0 = blockIdx.x * SCAN_CHUNK;
    int e1 = min(e0 + SCAN_CHUNK, N_EDGES);
    for (int e = e0 + (int)threadIdx.x; e < e1; e += blockDim.x) {
        int d = p.dst[e];
        if ((cbm[d >> 5] >> (d & 31)) & 1u) {
            int s = p.src[e];
            atomicOr(&p.markbm[s >> 5], 1u << (s & 31));
            lbuf[atomicAdd(&scnt[0], 1)] = e;
        }
    }
    __syncthreads();
    if (threadIdx.x == 0) scnt[1] = atomicAdd(&p.cnt[2], scnt[0]);
    __syncthreads();
    for (int t = threadIdx.x; t < scnt[0]; t += blockDim.x) {
        int gi = scnt[1] + t;
        if (gi < CAP2) astore(&p.list2[gi], lbuf[t]);
    }
}

// Phase 2 (fused): (a) compact marked nodes -> slots (first 13 blocks),
// (b) scan chunk: marked-dst edges -> list1, mark srcs in ndbm.
__device__ void ph_np2(const P& p, int* smem) {
    unsigned* mbs = (unsigned*)smem;        // markbm snapshot
    int* lbuf = smem + LBUF_OFF;
    int* scnt = smem + SCNT_OFF;
    for (int t = threadIdx.x; t < BM_WORDS; t += blockDim.x)
        mbs[t] = auload(&p.markbm[t]);
    if (threadIdx.x == 0) scnt[0] = 0;
    __syncthreads();

    // (a) node compaction: one word per global thread (wave-aggregated alloc)
    int gidx = blockIdx.x * blockDim.x + threadIdx.x;
    int lane = threadIdx.x & 63;
    if (blockIdx.x * (int)blockDim.x < BM_WORDS) {
        unsigned w = (gidx < BM_WORDS) ? mbs[gidx] : 0u;
        if (w) atomicOr(&p.ndbm[gidx], w);
        int c = __popc(w);
        int inc = c;
        for (int off = 1; off < 64; off <<= 1) {
            int t = __shfl_up(inc, off, 64);
            if (lane >= off) inc += t;
        }
        int total = __shfl(inc, 63, 64);
        if (total > 0) {
            int base = 0;
            if (lane == 63) base = atomicAdd(&p.cnt[0], total);
            base = __shfl(base, 63, 64);
            int slot = base + inc - c;
            unsigned ww = w;
            while (ww) {
                int b = __ffs(ww) - 1; ww &= ww - 1;
                int n = (gidx << 5) + b;
                if (slot < CAPS) { astore(&p.map1[n], slot); astore(&p.slotnode[slot], n); }
                else              astore(&p.map1[n], 0);
                ++slot;
            }
        }
    }

    // (b) list1 scan
    int e0 = blockIdx.x * SCAN_CHUNK;
    int e1 = min(e0 + SCAN_CHUNK, N_EDGES);
    for (int e = e0 + (int)threadIdx.x; e < e1; e += blockDim.x) {
        int d = p.dst[e];
        if ((mbs[d >> 5] >> (d & 31)) & 1u) {
            int s = p.src[e];
            atomicOr(&p.ndbm[s >> 5], 1u << (s & 31));
            lbuf[atomicAdd(&scnt[0], 1)] = e;
        }
    }
    __syncthreads();
    if (threadIdx.x == 0) scnt[1] = atomicAdd(&p.cnt[1], scnt[0]);
    __syncthreads();
    for (int t = threadIdx.x; t < scnt[0]; t += blockDim.x) {
        int gi = scnt[1] + t;
        if (gi < CAP1) astore(&p.list1[gi], lbuf[t]);
    }
}

// Phase 3: degree counting only for dst in the needed set (~31% of edges).
__device__ void ph_pass3(const P& p, int* smem) {
    unsigned* nds = (unsigned*)smem;        // ndbm snapshot
    for (int t = threadIdx.x; t < BM_WORDS; t += blockDim.x)
        nds[t] = auload(&p.ndbm[t]);
    __syncthreads();
    int e0 = blockIdx.x * SCAN_CHUNK;
    int e1 = min(e0 + SCAN_CHUNK, N_EDGES);
    for (int e = e0 + (int)threadIdx.x; e < e1; e += blockDim.x) {
        int d = p.dst[e];
        if ((nds[d >> 5] >> (d & 31)) & 1u) atomicAdd(&p.deg[d], 1u);
    }
}

// Phase 4: layer-1. Items = list1 edges + one self item per slot (bias folded
// in, NO relu here — l2 applies relu on read). One wave per item.
__device__ void ph_l1(const P& p, int* smem) {
    float* w1s = (float*)smem;              // 1024
    float* b1s = (float*)smem + 1024;       // 64
    for (int t = threadIdx.x; t < IN_CH * HID_CH; t += blockDim.x) w1s[t] = p.W1[t];
    if (threadIdx.x < HID_CH) b1s[threadIdx.x] = p.b1[threadIdx.x];
    __syncthreads();
    int lane = threadIdx.x & 63;
    int wid = blockIdx.x * (blockDim.x >> 6) + (threadIdx.x >> 6);
    int nw = gridDim.x * (blockDim.x >> 6);
    int n1 = min(aload(&p.cnt[1]), CAP1);
    int nS = min(aload(&p.cnt[0]), CAPS);
    for (int w = wid; w < n1 + nS; w += nw) {
        int n, slot; float scale, bias;
        if (w < n1) {
            int e = aload(&p.list1[w]);
            int s = p.src[e];
            int d = p.dst[e];
            slot = aload(&p.map1[d]);
            float rs = rsqrtf((float)(1u + auload(&p.deg[s])));
            float rd = rsqrtf((float)(1u + auload(&p.deg[d])));
            scale = rs * rd; bias = 0.0f; n = s;
        } else {
            slot = w - n1;
            n = aload(&p.slotnode[slot]);
            float r = rsqrtf((float)(1u + auload(&p.deg[n])));
            scale = r * r; bias = b1s[lane];
        }
        float xv = (lane < IN_CH) ? p.x[n * IN_CH + lane] : 0.0f;
        float t = 0.0f;
#pragma unroll
        for (int c = 0; c < IN_CH; ++c)
            t += __shfl(xv, c, 64) * w1s[c * HID_CH + lane];
        atomicAdd(&p.h1[(size_t)slot * HID_CH + lane], t * scale + bias);
    }
}

// Phase 5: layer-2. Items = list2 edges (ballot row resolution; duplicate rows
// each accumulate) + 128 self items. relu(h1) on read; atomics into out.
__device__ void ph_l2(const P& p, int* smem) {
    int* cent = smem;
    if (threadIdx.x < 128) cent[threadIdx.x] = p.ptr[threadIdx.x];
    __syncthreads();
    int lane = threadIdx.x & 63;
    int c0 = cent[lane];
    int c1v = cent[lane + 64];
    int wid = blockIdx.x * (blockDim.x >> 6) + (threadIdx.x >> 6);
    int nw = gridDim.x * (blockDim.x >> 6);
    int n2 = min(aload(&p.cnt[2]), CAP2);
    for (int w = wid; w < n2 + N_GRAPHS; w += nw) {
        int s, d, selfrow = -1;
        if (w < n2) {
            int e = aload(&p.list2[w]);
            s = p.src[e]; d = p.dst[e];
        } else {
            selfrow = w - n2;
            s = cent[selfrow]; d = s;
        }
        int slot = aload(&p.map1[s]); if (slot < 0) slot = 0;
        float rs = rsqrtf((float)(1u + auload(&p.deg[s])));
        float rd = rsqrtf((float)(1u + auload(&p.deg[d])));
        float norm = rs * rd;
        float myh = fmaxf(afload(&p.h1[(size_t)slot * HID_CH + lane]), 0.0f);
        float a0 = 0.0f, a1 = 0.0f;
#pragma unroll 8
        for (int j = 0; j < HID_CH; ++j) {
            float hv = __shfl(myh, j, 64);
            a0 += hv * p.W2[j * OUT_CH + lane];
            a1 += hv * p.W2[j * OUT_CH + lane + 64];
        }
        a0 *= norm; a1 *= norm;
        if (selfrow >= 0) {
            atomicAdd(&p.out[selfrow * OUT_CH + lane], a0);
            atomicAdd(&p.out[selfrow * OUT_CH + lane + 64], a1);
        } else {
            unsigned long long b0 = __ballot(c0 == d);
            unsigned long long b1 = __ballot(c1v == d);
            while (b0) {
                int r = __ffsll((long long)b0) - 1; b0 &= b0 - 1;
                atomicAdd(&p.out[r * OUT_CH + lane], a0);
                atomicAdd(&p.out[r * OUT_CH + lane + 64], a1);
            }
            while (b1) {
                int r = __ffsll((long long)b1) - 1 + 64; b1 &= b1 - 1;
                atomicAdd(&p.out[r * OUT_CH + lane], a0);
                atomicAdd(&p.out[r * OUT_CH + lane + 64], a1);
            }
        }
    }
}

// ---------------- kernels ----------------

// Prep: zero all cross-phase state via agent stores (no dirty L2 copies),
// init out = b2.
__global__ void k_prep(P p) {
    int i = blockIdx.x * blockDim.x + threadIdx.x;
    int st = gridDim.x * blockDim.x;
    for (int n = i; n < N_NODES; n += st) astore((int*)&p.deg[n], 0);
    for (int n = i; n < CAPS * HID_CH; n += st) afstore(&p.h1[n], 0.0f);
    for (int n = i; n < N_GRAPHS * OUT_CH; n += st) afstore(&p.out[n], p.b2[n & 127]);
    for (int n = i; n < BM_WORDS; n += st) {
        astore((int*)&p.markbm[n], 0);
        astore((int*)&p.ndbm[n], 0);
    }
    for (int n = i; n < BAR_INTS; n += st) astore(((int*)p.bar) + n, 0);
    if (i < 8) astore(&p.cnt[i], 0);
}

__global__ void __launch_bounds__(256) k_mega(P p) {
    __shared__ int smem[SMEM_INTS];
    ph_pass1(p, smem);  gbar(p.bar, 1);
    ph_np2(p, smem);    gbar(p.bar, 2);
    ph_pass3(p, smem);  gbar(p.bar, 3);
    ph_l1(p, smem);     gbar(p.bar, 4);
    ph_l2(p, smem);
}

// Standalone fallback kernels (kernel boundaries provide the sync).
__global__ void __launch_bounds__(256) k_p1(P p)  { __shared__ int s[SMEM_INTS]; ph_pass1(p, s); }
__global__ void __launch_bounds__(256) k_np2(P p) { __shared__ int s[SMEM_INTS]; ph_np2(p, s); }
__global__ void __launch_bounds__(256) k_p3(P p)  { __shared__ int s[SMEM_INTS]; ph_pass3(p, s); }
__global__ void __launch_bounds__(256) k_l1(P p)  { __shared__ int s[SMEM_INTS]; ph_l1(p, s); }
__global__ void __launch_bounds__(256) k_l2(P p)  { __shared__ int s[SMEM_INTS]; ph_l2(p, s); }

// ---------------- launch ----------------

extern "C" void kernel_launch(void* const* d_in, const int* in_sizes, int n_in,
                              void* d_out, int out_size, void* d_ws, size_t ws_size,
                              hipStream_t stream) {
    P p;
    p.x   = (const float*)d_in[0];          // fp32 (validated)
    const int* edge = (const int*)d_in[1];  // int32 (validated)
    p.src = edge;
    p.dst = edge + N_EDGES;
    p.ptr = (const int*)d_in[2];
    p.W1  = (const float*)d_in[3];
    p.b1  = (const float*)d_in[4];
    p.W2  = (const float*)d_in[5];
    p.b2  = (const float*)d_in[6];
    p.out = (float*)d_out;

    char* q = (char*)d_ws;
    auto alloc = [&](size_t bytes) {
        char* r = q; q += (bytes + 255) & ~size_t(255); return r;
    };
    p.deg      = (unsigned*)alloc((size_t)N_NODES * 4);
    p.map1     = (int*)     alloc((size_t)N_NODES * 4);
    p.slotnode = (int*)     alloc((size_t)CAPS * 4);
    p.list1    = (int*)     alloc((size_t)CAP1 * 4);
    p.list2    = (int*)     alloc((size_t)CAP2 * 4);
    p.h1       = (float*)   alloc((size_t)CAPS * HID_CH * 4);
    p.markbm   = (unsigned*)alloc((size_t)BM_WORDS * 4);
    p.ndbm     = (unsigned*)alloc((size_t)BM_WORDS * 4);
    p.cnt      = (int*)     alloc(256);
    p.bar      = (GBar*)    alloc(sizeof(GBar));

    hipLaunchKernelGGL(k_prep, dim3(256), dim3(256), 0, stream, p);

    void* args[] = { (void*)&p };
    hipError_t err = hipLaunchCooperativeKernel((const void*)k_mega,
                                                dim3(NBLK), dim3(256),
                                                args, 0, stream);
    if (err != hipSuccess) {
        (void)hipGetLastError();            // clear sticky error, use fallback
        hipLaunchKernelGGL(k_p1,  dim3(NBLK), dim3(256), 0, stream, p);
        hipLaunchKernelGGL(k_np2, dim3(NBLK), dim3(256), 0, stream, p);
        hipLaunchKernelGGL(k_p3,  dim3(NBLK), dim3(256), 0, stream, p);
        hipLaunchKernelGGL(k_l1,  dim3(NBLK), dim3(256), 0, stream, p);
        hipLaunchKernelGGL(k_l2,  dim3(NBLK), dim3(256), 0, stream, p);
    }
}

// Round 13
// 145.675 us; speedup vs baseline: 10.4235x; 1.6791x over previous
//
#include <hip/hip_runtime.h>

// Problem constants (fixed by the reference)
#define N_NODES   100000
#define N_EDGES   1600000
#define IN_CH     16
#define HID_CH    64
#define OUT_CH    128
#define N_GRAPHS  128

// Capacities. Expected: slots ~2.2K, list1 ~35K, list2 ~2K.
#define CAPS  4096
#define CAP1  65536
#define CAP2  16384

#define BM_WORDS ((N_NODES + 31) / 32)      // 3125 words = 12.5 KB bitmap

#define NBLK   2048                         // 8 blocks/CU x 256 CU, co-resident (validated R12)
#define GROUPS 32
#define GSIZE  (NBLK / GROUPS)              // 64 blocks per barrier leaf
#define SCAN_CHUNK ((N_EDGES + NBLK - 1) / NBLK)   // 782 edges/block

// LDS arena (ints): [0..3124] bitmap | w1s+b1s | cent ; lbuf@3136 ; scnt@4000
#define SMEM_INTS 4224
#define LBUF_OFF  3136
#define SCNT_OFF  4000

// ---- agent-scope (cache-bypassing, coherence-point) accessors ----
__device__ __forceinline__ int aload(const int* p) {
    return __hip_atomic_load(p, __ATOMIC_RELAXED, __HIP_MEMORY_SCOPE_AGENT);
}
__device__ __forceinline__ unsigned auload(const unsigned* p) {
    return __hip_atomic_load(p, __ATOMIC_RELAXED, __HIP_MEMORY_SCOPE_AGENT);
}
__device__ __forceinline__ float afload(const float* p) {
    return __hip_atomic_load(p, __ATOMIC_RELAXED, __HIP_MEMORY_SCOPE_AGENT);
}
__device__ __forceinline__ void astore(int* p, int v) {
    __hip_atomic_store(p, v, __ATOMIC_RELAXED, __HIP_MEMORY_SCOPE_AGENT);
}
__device__ __forceinline__ void afstore(float* p, float v) {
    __hip_atomic_store(p, v, __ATOMIC_RELAXED, __HIP_MEMORY_SCOPE_AGENT);
}

// ---- tree barrier state (monotonic; zeroed by k_prep each launch) ----
struct GBar { int leaf[GROUPS * 16]; int root[16]; int rootrel[16]; int leafrel[GROUPS * 16]; };
#define BAR_INTS ((int)(sizeof(GBar) / 4))

struct P {
    const float* x; const int* src; const int* dst; const int* ptr;
    const float* W1; const float* b1; const float* W2; const float* b2;
    float* out;
    unsigned* deg; int* map1; int* slotnode; int* list1; int* list2;
    float* h1; unsigned* markbm; unsigned* ndbm; int* cnt; GBar* bar;
};

// Fully RELAXED tree barrier. No acquire/release (no buffer_wbl2/buffer_inv
// L2 maintenance — the R12 suspect). Correctness: all cross-phase data ops are
// CP-serviced agent atomics; s_waitcnt vmcnt(0) guarantees this wave's stores
// reached the CP before the arrival tick; data-dependency chains order the
// barrier atomics themselves.
__device__ __forceinline__ void gbar(GBar* b, int k) {
    __syncthreads();                        // also drains vmcnt per wave
    if (threadIdx.x == 0) {
        asm volatile("s_waitcnt vmcnt(0) lgkmcnt(0)" ::: "memory");
        int g = blockIdx.x / GSIZE;
        int a = __hip_atomic_fetch_add(&b->leaf[g * 16], 1, __ATOMIC_RELAXED,
                                       __HIP_MEMORY_SCOPE_AGENT);
        if (a == GSIZE * k - 1) {           // last block of this group
            int r = __hip_atomic_fetch_add(&b->root[0], 1, __ATOMIC_RELAXED,
                                           __HIP_MEMORY_SCOPE_AGENT);
            if (r == GROUPS * k - 1) {
                __hip_atomic_store(&b->rootrel[0], k, __ATOMIC_RELAXED,
                                   __HIP_MEMORY_SCOPE_AGENT);
            } else {
                while (__hip_atomic_load(&b->rootrel[0], __ATOMIC_RELAXED,
                                         __HIP_MEMORY_SCOPE_AGENT) < k)
                    __builtin_amdgcn_s_sleep(2);
            }
            __hip_atomic_store(&b->leafrel[g * 16], k, __ATOMIC_RELAXED,
                               __HIP_MEMORY_SCOPE_AGENT);
        } else {
            while (__hip_atomic_load(&b->leafrel[g * 16], __ATOMIC_RELAXED,
                                     __HIP_MEMORY_SCOPE_AGENT) < k)
                __builtin_amdgcn_s_sleep(2);
        }
    }
    __syncthreads();
}

// ---------------- phases ----------------

// Phase 0: zero all cross-phase state via CP stores; out = b2.
__device__ void ph_zero(const P& p) {
    int i = blockIdx.x * blockDim.x + threadIdx.x;
    int st = gridDim.x * blockDim.x;
    for (int n = i; n < N_NODES; n += st) astore((int*)&p.deg[n], 0);
    for (int n = i; n < CAPS * HID_CH; n += st) afstore(&p.h1[n], 0.0f);
    for (int n = i; n < N_GRAPHS * OUT_CH; n += st) afstore(&p.out[n], p.b2[n & 127]);
    for (int n = i; n < BM_WORDS; n += st) {
        astore((int*)&p.markbm[n], 0);
        astore((int*)&p.ndbm[n], 0);
    }
    if (i < 16) astore(&p.cnt[i], 0);
}

// Phase 1: LDS central bitmap from ptr; scan chunk; central-dst edges -> list2,
// their srcs (and the centrals, via block 0) -> markbm.
__device__ void ph_pass1(const P& p, int* smem) {
    unsigned* cbm = (unsigned*)smem;
    int* lbuf = smem + LBUF_OFF;
    int* scnt = smem + SCNT_OFF;
    for (int t = threadIdx.x; t < BM_WORDS; t += blockDim.x) cbm[t] = 0u;
    if (threadIdx.x == 0) scnt[0] = 0;
    __syncthreads();
    if (threadIdx.x < N_GRAPHS) {
        int c = p.ptr[threadIdx.x];
        atomicOr(&cbm[c >> 5], 1u << (c & 31));
        if (blockIdx.x == 0)
            atomicOr(&p.markbm[c >> 5], 1u << (c & 31));
    }
    __syncthreads();
    int e0 = blockIdx.x * SCAN_CHUNK;
    int e1 = min(e0 + SCAN_CHUNK, N_EDGES);
    for (int e = e0 + (int)threadIdx.x; e < e1; e += blockDim.x) {
        int d = p.dst[e];
        if ((cbm[d >> 5] >> (d & 31)) & 1u) {
            int s = p.src[e];
            atomicOr(&p.markbm[s >> 5], 1u << (s & 31));
            lbuf[atomicAdd(&scnt[0], 1)] = e;
        }
    }
    __syncthreads();
    if (threadIdx.x == 0) scnt[1] = atomicAdd(&p.cnt[2], scnt[0]);
    __syncthreads();
    for (int t = threadIdx.x; t < scnt[0]; t += blockDim.x) {
        int gi = scnt[1] + t;
        if (gi < CAP2) astore(&p.list2[gi], lbuf[t]);
    }
}

// Phase 2 (fused): (a) compact marked nodes -> slots (first 13 blocks),
// (b) scan chunk: marked-dst edges -> list1, mark srcs in ndbm.
__device__ void ph_np2(const P& p, int* smem) {
    unsigned* mbs = (unsigned*)smem;        // markbm snapshot
    int* lbuf = smem + LBUF_OFF;
    int* scnt = smem + SCNT_OFF;
    for (int t = threadIdx.x; t < BM_WORDS; t += blockDim.x)
        mbs[t] = auload(&p.markbm[t]);
    if (threadIdx.x == 0) scnt[0] = 0;
    __syncthreads();

    // (a) node compaction: one word per global thread (wave-aggregated alloc)
    int gidx = blockIdx.x * blockDim.x + threadIdx.x;
    int lane = threadIdx.x & 63;
    if (blockIdx.x * (int)blockDim.x < BM_WORDS) {
        unsigned w = (gidx < BM_WORDS) ? mbs[gidx] : 0u;
        if (w) atomicOr(&p.ndbm[gidx], w);
        int c = __popc(w);
        int inc = c;
        for (int off = 1; off < 64; off <<= 1) {
            int t = __shfl_up(inc, off, 64);
            if (lane >= off) inc += t;
        }
        int total = __shfl(inc, 63, 64);
        if (total > 0) {
            int base = 0;
            if (lane == 63) base = atomicAdd(&p.cnt[0], total);
            base = __shfl(base, 63, 64);
            int slot = base + inc - c;
            unsigned ww = w;
            while (ww) {
                int b = __ffs(ww) - 1; ww &= ww - 1;
                int n = (gidx << 5) + b;
                if (slot < CAPS) { astore(&p.map1[n], slot); astore(&p.slotnode[slot], n); }
                else              astore(&p.map1[n], 0);
                ++slot;
            }
        }
    }

    // (b) list1 scan
    int e0 = blockIdx.x * SCAN_CHUNK;
    int e1 = min(e0 + SCAN_CHUNK, N_EDGES);
    for (int e = e0 + (int)threadIdx.x; e < e1; e += blockDim.x) {
        int d = p.dst[e];
        if ((mbs[d >> 5] >> (d & 31)) & 1u) {
            int s = p.src[e];
            atomicOr(&p.ndbm[s >> 5], 1u << (s & 31));
            lbuf[atomicAdd(&scnt[0], 1)] = e;
        }
    }
    __syncthreads();
    if (threadIdx.x == 0) scnt[1] = atomicAdd(&p.cnt[1], scnt[0]);
    __syncthreads();
    for (int t = threadIdx.x; t < scnt[0]; t += blockDim.x) {
        int gi = scnt[1] + t;
        if (gi < CAP1) astore(&p.list1[gi], lbuf[t]);
    }
}

// Phase 3: degree counting only for dst in the needed set (~31% of edges).
__device__ void ph_pass3(const P& p, int* smem) {
    unsigned* nds = (unsigned*)smem;        // ndbm snapshot
    for (int t = threadIdx.x; t < BM_WORDS; t += blockDim.x)
        nds[t] = auload(&p.ndbm[t]);
    __syncthreads();
    int e0 = blockIdx.x * SCAN_CHUNK;
    int e1 = min(e0 + SCAN_CHUNK, N_EDGES);
    for (int e = e0 + (int)threadIdx.x; e < e1; e += blockDim.x) {
        int d = p.dst[e];
        if ((nds[d >> 5] >> (d & 31)) & 1u) atomicAdd(&p.deg[d], 1u);
    }
}

// Phase 4: layer-1. Items = list1 edges + one self item per slot (bias folded
// in; relu applied by l2 on read). One wave per item.
__device__ void ph_l1(const P& p, int* smem) {
    float* w1s = (float*)smem;              // 1024 floats
    float* b1s = (float*)smem + 1024;       // 64 floats
    for (int t = threadIdx.x; t < IN_CH * HID_CH; t += blockDim.x) w1s[t] = p.W1[t];
    if (threadIdx.x < HID_CH) b1s[threadIdx.x] = p.b1[threadIdx.x];
    __syncthreads();
    int lane = threadIdx.x & 63;
    int wid = blockIdx.x * (blockDim.x >> 6) + (threadIdx.x >> 6);
    int nw = gridDim.x * (blockDim.x >> 6);
    int n1 = min(aload(&p.cnt[1]), CAP1);
    int nS = min(aload(&p.cnt[0]), CAPS);
    for (int w = wid; w < n1 + nS; w += nw) {
        int n, slot; float scale, bias;
        if (w < n1) {
            int e = aload(&p.list1[w]);
            int s = p.src[e];
            int d = p.dst[e];
            slot = aload(&p.map1[d]);
            float rs = rsqrtf((float)(1u + auload(&p.deg[s])));
            float rd = rsqrtf((float)(1u + auload(&p.deg[d])));
            scale = rs * rd; bias = 0.0f; n = s;
        } else {
            slot = w - n1;
            n = aload(&p.slotnode[slot]);
            float r = rsqrtf((float)(1u + auload(&p.deg[n])));
            scale = r * r; bias = b1s[lane];
        }
        float xv = (lane < IN_CH) ? p.x[n * IN_CH + lane] : 0.0f;
        float t = 0.0f;
#pragma unroll
        for (int c = 0; c < IN_CH; ++c)
            t += __shfl(xv, c, 64) * w1s[c * HID_CH + lane];
        atomicAdd(&p.h1[(size_t)slot * HID_CH + lane], t * scale + bias);
    }
}

// Phase 5: layer-2. Items = list2 edges (ballot row resolution; duplicate rows
// each accumulate) + 128 self items. relu(h1) on read; atomics into out.
__device__ void ph_l2(const P& p, int* smem) {
    int* cent = smem;
    if (threadIdx.x < 128) cent[threadIdx.x] = p.ptr[threadIdx.x];
    __syncthreads();
    int lane = threadIdx.x & 63;
    int c0 = cent[lane];
    int c1v = cent[lane + 64];
    int wid = blockIdx.x * (blockDim.x >> 6) + (threadIdx.x >> 6);
    int nw = gridDim.x * (blockDim.x >> 6);
    int n2 = min(aload(&p.cnt[2]), CAP2);
    for (int w = wid; w < n2 + N_GRAPHS; w += nw) {
        int s, d, selfrow = -1;
        if (w < n2) {
            int e = aload(&p.list2[w]);
            s = p.src[e]; d = p.dst[e];
        } else {
            selfrow = w - n2;
            s = cent[selfrow]; d = s;
        }
        int slot = aload(&p.map1[s]); if (slot < 0) slot = 0;
        float rs = rsqrtf((float)(1u + auload(&p.deg[s])));
        float rd = rsqrtf((float)(1u + auload(&p.deg[d])));
        float norm = rs * rd;
        float myh = fmaxf(afload(&p.h1[(size_t)slot * HID_CH + lane]), 0.0f);
        float a0 = 0.0f, a1 = 0.0f;
#pragma unroll 8
        for (int j = 0; j < HID_CH; ++j) {
            float hv = __shfl(myh, j, 64);
            a0 += hv * p.W2[j * OUT_CH + lane];
            a1 += hv * p.W2[j * OUT_CH + lane + 64];
        }
        a0 *= norm; a1 *= norm;
        if (selfrow >= 0) {
            atomicAdd(&p.out[selfrow * OUT_CH + lane], a0);
            atomicAdd(&p.out[selfrow * OUT_CH + lane + 64], a1);
        } else {
            unsigned long long b0 = __ballot(c0 == d);
            unsigned long long b1 = __ballot(c1v == d);
            while (b0) {
                int r = __ffsll((long long)b0) - 1; b0 &= b0 - 1;
                atomicAdd(&p.out[r * OUT_CH + lane], a0);
                atomicAdd(&p.out[r * OUT_CH + lane + 64], a1);
            }
            while (b1) {
                int r = __ffsll((long long)b1) - 1 + 64; b1 &= b1 - 1;
                atomicAdd(&p.out[r * OUT_CH + lane], a0);
                atomicAdd(&p.out[r * OUT_CH + lane + 64], a1);
            }
        }
    }
}

// ---------------- kernels ----------------

// Prep: zero ONLY the barrier state (tiny, 1 block).
__global__ void k_prep(P p) {
    int* b = (int*)p.bar;
    for (int i = threadIdx.x; i < BAR_INTS; i += blockDim.x) astore(b + i, 0);
}

__global__ void __launch_bounds__(256) k_mega(P p) {
    __shared__ int smem[SMEM_INTS];
    ph_zero(p);         gbar(p.bar, 1);
    ph_pass1(p, smem);  gbar(p.bar, 2);
    ph_np2(p, smem);    gbar(p.bar, 3);
    ph_pass3(p, smem);  gbar(p.bar, 4);
    ph_l1(p, smem);     gbar(p.bar, 5);
    ph_l2(p, smem);
}

// Standalone fallback kernels (kernel boundaries provide the sync).
__global__ void k_zero_s(P p) { ph_zero(p); }
__global__ void __launch_bounds__(256) k_p1(P p)  { __shared__ int s[SMEM_INTS]; ph_pass1(p, s); }
__global__ void __launch_bounds__(256) k_np2(P p) { __shared__ int s[SMEM_INTS]; ph_np2(p, s); }
__global__ void __launch_bounds__(256) k_p3(P p)  { __shared__ int s[SMEM_INTS]; ph_pass3(p, s); }
__global__ void __launch_bounds__(256) k_l1(P p)  { __shared__ int s[SMEM_INTS]; ph_l1(p, s); }
__global__ void __launch_bounds__(256) k_l2(P p)  { __shared__ int s[SMEM_INTS]; ph_l2(p, s); }

// ---------------- launch ----------------

extern "C" void kernel_launch(void* const* d_in, const int* in_sizes, int n_in,
                              void* d_out, int out_size, void* d_ws, size_t ws_size,
                              hipStream_t stream) {
    P p;
    p.x   = (const float*)d_in[0];          // fp32 (validated)
    const int* edge = (const int*)d_in[1];  // int32 (validated)
    p.src = edge;
    p.dst = edge + N_EDGES;
    p.ptr = (const int*)d_in[2];
    p.W1  = (const float*)d_in[3];
    p.b1  = (const float*)d_in[4];
    p.W2  = (const float*)d_in[5];
    p.b2  = (const float*)d_in[6];
    p.out = (float*)d_out;

    char* q = (char*)d_ws;
    auto alloc = [&](size_t bytes) {
        char* r = q; q += (bytes + 255) & ~size_t(255); return r;
    };
    p.deg      = (unsigned*)alloc((size_t)N_NODES * 4);
    p.map1     = (int*)     alloc((size_t)N_NODES * 4);
    p.slotnode = (int*)     alloc((size_t)CAPS * 4);
    p.list1    = (int*)     alloc((size_t)CAP1 * 4);
    p.list2    = (int*)     alloc((size_t)CAP2 * 4);
    p.h1       = (float*)   alloc((size_t)CAPS * HID_CH * 4);
    p.markbm   = (unsigned*)alloc((size_t)BM_WORDS * 4);
    p.ndbm     = (unsigned*)alloc((size_t)BM_WORDS * 4);
    p.cnt      = (int*)     alloc(256);
    p.bar      = (GBar*)    alloc(sizeof(GBar));

    hipLaunchKernelGGL(k_prep, dim3(1), dim3(256), 0, stream, p);

    void* args[] = { (void*)&p };
    hipError_t err = hipLaunchCooperativeKernel((const void*)k_mega,
                                                dim3(NBLK), dim3(256),
                                                args, 0, stream);
    if (err != hipSuccess) {
        (void)hipGetLastError();            // clear sticky error, use fallback
        hipLaunchKernelGGL(k_zero_s, dim3(1024), dim3(256), 0, stream, p);
        hipLaunchKernelGGL(k_p1,  dim3(NBLK), dim3(256), 0, stream, p);
        hipLaunchKernelGGL(k_np2, dim3(NBLK), dim3(256), 0, stream, p);
        hipLaunchKernelGGL(k_p3,  dim3(NBLK), dim3(256), 0, stream, p);
        hipLaunchKernelGGL(k_l1,  dim3(NBLK), dim3(256), 0, stream, p);
        hipLaunchKernelGGL(k_l2,  dim3(NBLK), dim3(256), 0, stream, p);
    }
}

// Round 15
// 135.709 us; speedup vs baseline: 11.1889x; 1.0734x over previous
//
#include <hip/hip_runtime.h>

// Problem constants (fixed by the reference)
#define N_NODES   100000
#define N_EDGES   1600000
#define IN_CH     16
#define HID_CH    64
#define OUT_CH    128
#define N_GRAPHS  128

// Capacities. Expected: slots ~2.2K, list1 ~35K, list2 ~2K.
#define CAPS  4096
#define CAP1  65536
#define CAP2  16384

#define BM_WORDS ((N_NODES + 31) / 32)      // 3125 words; padded to 3136/3200
#define BM_PAD   3200

#define NBLK   2048                         // 8 blocks/CU x 256 CU, co-resident
#define GROUPS 32
#define GSIZE  (NBLK / GROUPS)
#define SCAN_CHUNK 784                      // 4-aligned; NBLK*784 >= N_EDGES

// LDS arena (ints): [0..3135] bitmap | w1s(1024)+b1s(64) | cent(128)
//                   lbuf @3136 (784) ; scnt @4000
#define SMEM_INTS 4224
#define LBUF_OFF  3136
#define SCNT_OFF  4000

typedef int      iv4 __attribute__((ext_vector_type(4)));
typedef unsigned uv4 __attribute__((ext_vector_type(4)));
typedef float    fv4 __attribute__((ext_vector_type(4)));

// ---- agent-scope scalar accessors (CP-serviced) ----
__device__ __forceinline__ int aload(const int* p) {
    return __hip_atomic_load(p, __ATOMIC_RELAXED, __HIP_MEMORY_SCOPE_AGENT);
}
__device__ __forceinline__ unsigned auload(const unsigned* p) {
    return __hip_atomic_load(p, __ATOMIC_RELAXED, __HIP_MEMORY_SCOPE_AGENT);
}
__device__ __forceinline__ float afload(const float* p) {
    return __hip_atomic_load(p, __ATOMIC_RELAXED, __HIP_MEMORY_SCOPE_AGENT);
}
__device__ __forceinline__ void astore(int* p, int v) {
    __hip_atomic_store(p, v, __ATOMIC_RELAXED, __HIP_MEMORY_SCOPE_AGENT);
}

// ---- CP-serviced 16B vector ops (sc0 sc1 = bypass L1+L2, memory-side) ----
__device__ __forceinline__ void cpstore4u(unsigned* p, uv4 v) {
    asm volatile("global_store_dwordx4 %0, %1, off sc0 sc1" :: "v"(p), "v"(v) : "memory");
}
__device__ __forceinline__ void cpstore4f(float* p, fv4 v) {
    asm volatile("global_store_dwordx4 %0, %1, off sc0 sc1" :: "v"(p), "v"(v) : "memory");
}

// Snapshot padded bitmap (3136 words) global->LDS: 196 threads x 4 dwordx4.
// EARLY-CLOBBER "=&v" is load-bearing: without it the allocator may alias the
// output regs with the address pair %4, and the first load corrupts the
// address for the remaining three (R14 crash).
__device__ __forceinline__ void snap_bm(const unsigned* g, unsigned* lds) {
    int t = threadIdx.x;
    if (t < 196) {
        const unsigned* ptr = g + t * 16;
        uv4 a, b, c, d;
        asm volatile(
            "global_load_dwordx4 %0, %4, off sc0 sc1\n\t"
            "global_load_dwordx4 %1, %4, off offset:16 sc0 sc1\n\t"
            "global_load_dwordx4 %2, %4, off offset:32 sc0 sc1\n\t"
            "global_load_dwordx4 %3, %4, off offset:48 sc0 sc1\n\t"
            "s_waitcnt vmcnt(0)"
            : "=&v"(a), "=&v"(b), "=&v"(c), "=&v"(d)
            : "v"(ptr) : "memory");
        *(uv4*)(lds + t * 16)      = a;
        *(uv4*)(lds + t * 16 + 4)  = b;
        *(uv4*)(lds + t * 16 + 8)  = c;
        *(uv4*)(lds + t * 16 + 12) = d;
    }
    __syncthreads();
}

// ---- tree barrier (monotonic; zeroed by k_prep each launch) ----
struct GBar { int leaf[GROUPS * 16]; int root[16]; int rootrel[16]; int leafrel[GROUPS * 16]; };
#define BAR_INTS ((int)(sizeof(GBar) / 4))

struct P {
    const float* x; const int* src; const int* dst; const int* ptr;
    const float* W1; const float* b1; const float* W2; const float* b2;
    float* out;
    unsigned* deg; int* map1; int* slotnode; int* list1; int* list2;
    float* h1; unsigned* markbm; unsigned* ndbm; int* cnt; GBar* bar;
};

// Fully RELAXED tree barrier (validated R13: no L2 wb/inv). All threads drain
// vmcnt so asm CP stores are at the coherence point before arrival.
__device__ __forceinline__ void gbar(GBar* b, int k) {
    asm volatile("s_waitcnt vmcnt(0) lgkmcnt(0)" ::: "memory");
    __syncthreads();
    if (threadIdx.x == 0) {
        int g = blockIdx.x / GSIZE;
        int a = __hip_atomic_fetch_add(&b->leaf[g * 16], 1, __ATOMIC_RELAXED,
                                       __HIP_MEMORY_SCOPE_AGENT);
        if (a == GSIZE * k - 1) {
            int r = __hip_atomic_fetch_add(&b->root[0], 1, __ATOMIC_RELAXED,
                                           __HIP_MEMORY_SCOPE_AGENT);
            if (r == GROUPS * k - 1) {
                __hip_atomic_store(&b->rootrel[0], k, __ATOMIC_RELAXED,
                                   __HIP_MEMORY_SCOPE_AGENT);
            } else {
                while (__hip_atomic_load(&b->rootrel[0], __ATOMIC_RELAXED,
                                         __HIP_MEMORY_SCOPE_AGENT) < k)
                    __builtin_amdgcn_s_sleep(2);
            }
            __hip_atomic_store(&b->leafrel[g * 16], k, __ATOMIC_RELAXED,
                               __HIP_MEMORY_SCOPE_AGENT);
        } else {
            while (__hip_atomic_load(&b->leafrel[g * 16], __ATOMIC_RELAXED,
                                     __HIP_MEMORY_SCOPE_AGENT) < k)
                __builtin_amdgcn_s_sleep(2);
        }
    }
    __syncthreads();
}

// ---------------- phases ----------------

// Phase 1 (fused): zero deg/h1 + out=b2 (CP vec stores) AND central-dst edge
// scan (LDS central bitmap from ptr) -> list2; srcs (+centrals) -> markbm.
__device__ void ph_zp1(const P& p, int* smem) {
    unsigned* cbm = (unsigned*)smem;
    int* lbuf = smem + LBUF_OFF;
    int* scnt = smem + SCNT_OFF;
    for (int t = threadIdx.x; t < 3136; t += blockDim.x) cbm[t] = 0u;
    if (threadIdx.x == 0) scnt[0] = 0;
    __syncthreads();
    if (threadIdx.x < N_GRAPHS) {
        int c = p.ptr[threadIdx.x];
        atomicOr(&cbm[c >> 5], 1u << (c & 31));
        if (blockIdx.x == 0)
            atomicOr(&p.markbm[c >> 5], 1u << (c & 31));
    }
    // global zeroing (independent of the scan; CP vec stores, 4x fewer ops)
    int gid = blockIdx.x * blockDim.x + threadIdx.x;
    int gst = gridDim.x * blockDim.x;
    uv4 z4 = {0u, 0u, 0u, 0u};
    for (int i = gid; i < N_NODES / 4; i += gst)
        cpstore4u((unsigned*)p.deg + i * 4, z4);
    for (int i = gid; i < (CAPS * HID_CH) / 4; i += gst)
        cpstore4f(p.h1 + i * 4, (fv4){0.f, 0.f, 0.f, 0.f});
    for (int i = gid; i < (N_GRAPHS * OUT_CH) / 4; i += gst) {
        int c = (i * 4) & 127;
        fv4 v = { p.b2[c], p.b2[c + 1], p.b2[c + 2], p.b2[c + 3] };
        cpstore4f(p.out + i * 4, v);
    }
    __syncthreads();
    // vectorized edge scan (int4; N_EDGES % 4 == 0 so no partial vector)
    if (threadIdx.x < SCAN_CHUNK / 4) {
        int e = blockIdx.x * SCAN_CHUNK + threadIdx.x * 4;
        if (e < N_EDGES) {
            iv4 d4 = *(const iv4*)(p.dst + e);
#pragma unroll
            for (int k = 0; k < 4; ++k) {
                int d = d4[k];
                if ((cbm[d >> 5] >> (d & 31)) & 1u) {
                    int s = p.src[e + k];
                    atomicOr(&p.markbm[s >> 5], 1u << (s & 31));
                    lbuf[atomicAdd(&scnt[0], 1)] = e + k;
                }
            }
        }
    }
    __syncthreads();
    if (threadIdx.x == 0) scnt[1] = atomicAdd(&p.cnt[2], scnt[0]);
    __syncthreads();
    for (int t = threadIdx.x; t < scnt[0]; t += blockDim.x) {
        int gi = scnt[1] + t;
        if (gi < CAP2) astore(&p.list2[gi], lbuf[t]);
    }
}

// Phase 2 (fused): snapshot markbm (vec CP); (a) compact marked -> slots
// (blocks 0..12, wave-aggregated); (b) scan: marked-dst edges -> list1,
// srcs -> ndbm.
__device__ void ph_np2(const P& p, int* smem) {
    unsigned* mbs = (unsigned*)smem;
    int* lbuf = smem + LBUF_OFF;
    int* scnt = smem + SCNT_OFF;
    if (threadIdx.x == 0) scnt[0] = 0;
    snap_bm(p.markbm, mbs);                 // ends with __syncthreads

    // (a) node compaction
    int gidx = blockIdx.x * blockDim.x + threadIdx.x;
    int lane = threadIdx.x & 63;
    if (blockIdx.x * (int)blockDim.x < BM_WORDS) {
        unsigned w = (gidx < BM_WORDS) ? mbs[gidx] : 0u;
        if (w) atomicOr(&p.ndbm[gidx], w);
        int c = __popc(w);
        int inc = c;
        for (int off = 1; off < 64; off <<= 1) {
            int t = __shfl_up(inc, off, 64);
            if (lane >= off) inc += t;
        }
        int total = __shfl(inc, 63, 64);
        if (total > 0) {
            int base = 0;
            if (lane == 63) base = atomicAdd(&p.cnt[0], total);
            base = __shfl(base, 63, 64);
            int slot = base + inc - c;
            unsigned ww = w;
            while (ww) {
                int b = __ffs(ww) - 1; ww &= ww - 1;
                int n = (gidx << 5) + b;
                if (slot < CAPS) { astore(&p.map1[n], slot); astore(&p.slotnode[slot], n); }
                else              astore(&p.map1[n], 0);
                ++slot;
            }
        }
    }

    // (b) vectorized list1 scan
    if (threadIdx.x < SCAN_CHUNK / 4) {
        int e = blockIdx.x * SCAN_CHUNK + threadIdx.x * 4;
        if (e < N_EDGES) {
            iv4 d4 = *(const iv4*)(p.dst + e);
#pragma unroll
            for (int k = 0; k < 4; ++k) {
                int d = d4[k];
                if ((mbs[d >> 5] >> (d & 31)) & 1u) {
                    int s = p.src[e + k];
                    atomicOr(&p.ndbm[s >> 5], 1u << (s & 31));
                    lbuf[atomicAdd(&scnt[0], 1)] = e + k;
                }
            }
        }
    }
    __syncthreads();
    if (threadIdx.x == 0) scnt[1] = atomicAdd(&p.cnt[1], scnt[0]);
    __syncthreads();
    for (int t = threadIdx.x; t < scnt[0]; t += blockDim.x) {
        int gi = scnt[1] + t;
        if (gi < CAP1) astore(&p.list1[gi], lbuf[t]);
    }
}

// Phase 3: snapshot ndbm (vec CP); degree count only for dst in needed set.
__device__ void ph_p3(const P& p, int* smem) {
    unsigned* nds = (unsigned*)smem;
    snap_bm(p.ndbm, nds);                   // ends with __syncthreads
    if (threadIdx.x < SCAN_CHUNK / 4) {
        int e = blockIdx.x * SCAN_CHUNK + threadIdx.x * 4;
        if (e < N_EDGES) {
            iv4 d4 = *(const iv4*)(p.dst + e);
#pragma unroll
            for (int k = 0; k < 4; ++k) {
                int d = d4[k];
                if ((nds[d >> 5] >> (d & 31)) & 1u) atomicAdd(&p.deg[d], 1u);
            }
        }
    }
}

// Phase 4: layer-1. Items = list1 edges + one self item per slot (bias folded;
// relu applied by l2 on read). One wave per item.
__device__ void ph_l1(const P& p, int* smem) {
    float* w1s = (float*)smem;              // 1024 floats
    float* b1s = (float*)smem + 1024;       // 64 floats
    for (int t = threadIdx.x; t < IN_CH * HID_CH; t += blockDim.x) w1s[t] = p.W1[t];
    if (threadIdx.x < HID_CH) b1s[threadIdx.x] = p.b1[threadIdx.x];
    __syncthreads();
    int lane = threadIdx.x & 63;
    int wid = blockIdx.x * (blockDim.x >> 6) + (threadIdx.x >> 6);
    int nw = gridDim.x * (blockDim.x >> 6);
    int n1 = min(aload(&p.cnt[1]), CAP1);
    int nS = min(aload(&p.cnt[0]), CAPS);
    for (int w = wid; w < n1 + nS; w += nw) {
        int n, slot; float scale, bias;
        if (w < n1) {
            int e = aload(&p.list1[w]);
            int s = p.src[e];
            int d = p.dst[e];
            slot = aload(&p.map1[d]);
            float rs = rsqrtf((float)(1u + auload(&p.deg[s])));
            float rd = rsqrtf((float)(1u + auload(&p.deg[d])));
            scale = rs * rd; bias = 0.0f; n = s;
        } else {
            slot = w - n1;
            n = aload(&p.slotnode[slot]);
            float r = rsqrtf((float)(1u + auload(&p.deg[n])));
            scale = r * r; bias = b1s[lane];
        }
        float xv = (lane < IN_CH) ? p.x[n * IN_CH + lane] : 0.0f;
        float t = 0.0f;
#pragma unroll
        for (int c = 0; c < IN_CH; ++c)
            t += __shfl(xv, c, 64) * w1s[c * HID_CH + lane];
        atomicAdd(&p.h1[(size_t)slot * HID_CH + lane], t * scale + bias);
    }
}

// Phase 5: layer-2. Items = list2 edges (ballot row resolution; duplicate rows
// each accumulate) + 128 self items. relu(h1) on read; atomics into out.
__device__ void ph_l2(const P& p, int* smem) {
    int* cent = smem;
    if (threadIdx.x < 128) cent[threadIdx.x] = p.ptr[threadIdx.x];
    __syncthreads();
    int lane = threadIdx.x & 63;
    int c0 = cent[lane];
    int c1v = cent[lane + 64];
    int wid = blockIdx.x * (blockDim.x >> 6) + (threadIdx.x >> 6);
    int nw = gridDim.x * (blockDim.x >> 6);
    int n2 = min(aload(&p.cnt[2]), CAP2);
    for (int w = wid; w < n2 + N_GRAPHS; w += nw) {
        int s, d, selfrow = -1;
        if (w < n2) {
            int e = aload(&p.list2[w]);
            s = p.src[e]; d = p.dst[e];
        } else {
            selfrow = w - n2;
            s = cent[selfrow]; d = s;
        }
        int slot = aload(&p.map1[s]); if (slot < 0) slot = 0;
        float rs = rsqrtf((float)(1u + auload(&p.deg[s])));
        float rd = rsqrtf((float)(1u + auload(&p.deg[d])));
        float norm = rs * rd;
        float myh = fmaxf(afload(&p.h1[(size_t)slot * HID_CH + lane]), 0.0f);
        float a0 = 0.0f, a1 = 0.0f;
#pragma unroll 8
        for (int j = 0; j < HID_CH; ++j) {
            float hv = __shfl(myh, j, 64);
            a0 += hv * p.W2[j * OUT_CH + lane];
            a1 += hv * p.W2[j * OUT_CH + lane + 64];
        }
        a0 *= norm; a1 *= norm;
        if (selfrow >= 0) {
            atomicAdd(&p.out[selfrow * OUT_CH + lane], a0);
            atomicAdd(&p.out[selfrow * OUT_CH + lane + 64], a1);
        } else {
            unsigned long long b0 = __ballot(c0 == d);
            unsigned long long b1 = __ballot(c1v == d);
            while (b0) {
                int r = __ffsll((long long)b0) - 1; b0 &= b0 - 1;
                atomicAdd(&p.out[r * OUT_CH + lane], a0);
                atomicAdd(&p.out[r * OUT_CH + lane + 64], a1);
            }
            while (b1) {
                int r = __ffsll((long long)b1) - 1 + 64; b1 &= b1 - 1;
                atomicAdd(&p.out[r * OUT_CH + lane], a0);
                atomicAdd(&p.out[r * OUT_CH + lane + 64], a1);
            }
        }
    }
}

// ---------------- kernels ----------------

// Prep (separate dispatch): zero barrier, bitmaps, counters via CP stores.
__global__ void k_prep(P p) {
    int i = blockIdx.x * blockDim.x + threadIdx.x;
    int st = gridDim.x * blockDim.x;
    uv4 z4 = {0u, 0u, 0u, 0u};
    for (int n = i; n < BM_PAD / 4; n += st) {
        cpstore4u(p.markbm + n * 4, z4);
        cpstore4u(p.ndbm + n * 4, z4);
    }
    for (int n = i; n < BAR_INTS; n += st) astore(((int*)p.bar) + n, 0);
    if (i < 16) astore(&p.cnt[i], 0);
}

__global__ void __launch_bounds__(256) k_mega(P p) {
    __shared__ int smem[SMEM_INTS];
    ph_zp1(p, smem);  gbar(p.bar, 1);
    ph_np2(p, smem);  gbar(p.bar, 2);
    ph_p3(p, smem);   gbar(p.bar, 3);
    ph_l1(p, smem);   gbar(p.bar, 4);
    ph_l2(p, smem);
}

// Standalone fallback kernels (kernel boundaries provide the sync).
__global__ void __launch_bounds__(256) k_zp1(P p) { __shared__ int s[SMEM_INTS]; ph_zp1(p, s); }
__global__ void __launch_bounds__(256) k_np2(P p) { __shared__ int s[SMEM_INTS]; ph_np2(p, s); }
__global__ void __launch_bounds__(256) k_p3(P p)  { __shared__ int s[SMEM_INTS]; ph_p3(p, s); }
__global__ void __launch_bounds__(256) k_l1(P p)  { __shared__ int s[SMEM_INTS]; ph_l1(p, s); }
__global__ void __launch_bounds__(256) k_l2(P p)  { __shared__ int s[SMEM_INTS]; ph_l2(p, s); }

// ---------------- launch ----------------

extern "C" void kernel_launch(void* const* d_in, const int* in_sizes, int n_in,
                              void* d_out, int out_size, void* d_ws, size_t ws_size,
                              hipStream_t stream) {
    P p;
    p.x   = (const float*)d_in[0];          // fp32 (validated)
    const int* edge = (const int*)d_in[1];  // int32 (validated)
    p.src = edge;
    p.dst = edge + N_EDGES;
    p.ptr = (const int*)d_in[2];
    p.W1  = (const float*)d_in[3];
    p.b1  = (const float*)d_in[4];
    p.W2  = (const float*)d_in[5];
    p.b2  = (const float*)d_in[6];
    p.out = (float*)d_out;

    char* q = (char*)d_ws;
    auto alloc = [&](size_t bytes) {
        char* r = q; q += (bytes + 255) & ~size_t(255); return r;
    };
    p.deg      = (unsigned*)alloc((size_t)N_NODES * 4);
    p.map1     = (int*)     alloc((size_t)N_NODES * 4);
    p.slotnode = (int*)     alloc((size_t)CAPS * 4);
    p.list1    = (int*)     alloc((size_t)CAP1 * 4);
    p.list2    = (int*)     alloc((size_t)CAP2 * 4);
    p.h1       = (float*)   alloc((size_t)CAPS * HID_CH * 4);
    p.markbm   = (unsigned*)alloc((size_t)BM_PAD * 4);
    p.ndbm     = (unsigned*)alloc((size_t)BM_PAD * 4);
    p.cnt      = (int*)     alloc(256);
    p.bar      = (GBar*)    alloc(sizeof(GBar));

    hipLaunchKernelGGL(k_prep, dim3(8), dim3(256), 0, stream, p);

    void* args[] = { (void*)&p };
    hipError_t err = hipLaunchCooperativeKernel((const void*)k_mega,
                                                dim3(NBLK), dim3(256),
                                                args, 0, stream);
    if (err != hipSuccess) {
        (void)hipGetLastError();            // clear sticky error, use fallback
        hipLaunchKernelGGL(k_zp1, dim3(NBLK), dim3(256), 0, stream, p);
        hipLaunchKernelGGL(k_np2, dim3(NBLK), dim3(256), 0, stream, p);
        hipLaunchKernelGGL(k_p3,  dim3(NBLK), dim3(256), 0, stream, p);
        hipLaunchKernelGGL(k_l1,  dim3(NBLK), dim3(256), 0, stream, p);
        hipLaunchKernelGGL(k_l2,  dim3(NBLK), dim3(256), 0, stream, p);
    }
}

// Round 16
// 109.377 us; speedup vs baseline: 13.8826x; 1.2407x over previous
//
#include <hip/hip_runtime.h>

// Problem constants (fixed by the reference)
#define N_NODES   100000
#define N_EDGES   1600000
#define IN_CH     16
#define HID_CH    64
#define OUT_CH    128
#define N_GRAPHS  128

// Capacities. Expected: slots ~2.2K, list1 ~35K, list2 ~2K.
#define CAPS  4096
#define CAP1  65536
#define CAP2  16384

#define BM_WORDS ((N_NODES + 31) / 32)      // 3125 words; padded to 3136/3200
#define BM_PAD   3200

#define NBLK   2048                         // 8 blocks/CU x 256 CU
#define GROUPS 32
#define GSIZE  (NBLK / GROUPS)
#define SCAN_CHUNK 784                      // 4-aligned; NBLK*784 >= N_EDGES

// LDS arena (ints)
#define SMEM_INTS 4224
#define LBUF_OFF  3136
#define SCNT_OFF  4000

typedef int      iv4 __attribute__((ext_vector_type(4)));
typedef unsigned uv4 __attribute__((ext_vector_type(4)));
typedef float    fv4 __attribute__((ext_vector_type(4)));

// ---- agent-scope scalar accessors (CP-serviced) ----
__device__ __forceinline__ int aload(const int* p) {
    return __hip_atomic_load(p, __ATOMIC_RELAXED, __HIP_MEMORY_SCOPE_AGENT);
}
__device__ __forceinline__ unsigned auload(const unsigned* p) {
    return __hip_atomic_load(p, __ATOMIC_RELAXED, __HIP_MEMORY_SCOPE_AGENT);
}
__device__ __forceinline__ float afload(const float* p) {
    return __hip_atomic_load(p, __ATOMIC_RELAXED, __HIP_MEMORY_SCOPE_AGENT);
}
__device__ __forceinline__ void astore(int* p, int v) {
    __hip_atomic_store(p, v, __ATOMIC_RELAXED, __HIP_MEMORY_SCOPE_AGENT);
}

// ---- CP-serviced 16B vector ops (sc0 sc1 = bypass L1+L2, memory-side) ----
__device__ __forceinline__ void cpstore4u(unsigned* p, uv4 v) {
    asm volatile("global_store_dwordx4 %0, %1, off sc0 sc1" :: "v"(p), "v"(v) : "memory");
}
__device__ __forceinline__ void cpstore4f(float* p, fv4 v) {
    asm volatile("global_store_dwordx4 %0, %1, off sc0 sc1" :: "v"(p), "v"(v) : "memory");
}

// Snapshot padded bitmap (3136 words) global->LDS: 196 threads x 4 dwordx4.
// "=&v" early-clobber is load-bearing (R14 crash without it).
__device__ __forceinline__ void snap_bm(const unsigned* g, unsigned* lds) {
    int t = threadIdx.x;
    if (t < 196) {
        const unsigned* ptr = g + t * 16;
        uv4 a, b, c, d;
        asm volatile(
            "global_load_dwordx4 %0, %4, off sc0 sc1\n\t"
            "global_load_dwordx4 %1, %4, off offset:16 sc0 sc1\n\t"
            "global_load_dwordx4 %2, %4, off offset:32 sc0 sc1\n\t"
            "global_load_dwordx4 %3, %4, off offset:48 sc0 sc1\n\t"
            "s_waitcnt vmcnt(0)"
            : "=&v"(a), "=&v"(b), "=&v"(c), "=&v"(d)
            : "v"(ptr) : "memory");
        *(uv4*)(lds + t * 16)      = a;
        *(uv4*)(lds + t * 16 + 4)  = b;
        *(uv4*)(lds + t * 16 + 8)  = c;
        *(uv4*)(lds + t * 16 + 12) = d;
    }
    __syncthreads();
}

// ---- tree barrier (kept for the coop variant; unused this round) ----
struct GBar { int leaf[GROUPS * 16]; int root[16]; int rootrel[16]; int leafrel[GROUPS * 16]; };
#define BAR_INTS ((int)(sizeof(GBar) / 4))

struct P {
    const float* x; const int* src; const int* dst; const int* ptr;
    const float* W1; const float* b1; const float* W2; const float* b2;
    float* out;
    unsigned* deg; int* map1; int* slotnode; int* list1; int* list2;
    float* h1; unsigned* markbm; unsigned* ndbm; int* cnt; GBar* bar;
};

__device__ __forceinline__ void gbar(GBar* b, int k) {
    asm volatile("s_waitcnt vmcnt(0) lgkmcnt(0)" ::: "memory");
    __syncthreads();
    if (threadIdx.x == 0) {
        int g = blockIdx.x / GSIZE;
        int a = __hip_atomic_fetch_add(&b->leaf[g * 16], 1, __ATOMIC_RELAXED,
                                       __HIP_MEMORY_SCOPE_AGENT);
        if (a == GSIZE * k - 1) {
            int r = __hip_atomic_fetch_add(&b->root[0], 1, __ATOMIC_RELAXED,
                                           __HIP_MEMORY_SCOPE_AGENT);
            if (r == GROUPS * k - 1) {
                __hip_atomic_store(&b->rootrel[0], k, __ATOMIC_RELAXED,
                                   __HIP_MEMORY_SCOPE_AGENT);
            } else {
                while (__hip_atomic_load(&b->rootrel[0], __ATOMIC_RELAXED,
                                         __HIP_MEMORY_SCOPE_AGENT) < k)
                    __builtin_amdgcn_s_sleep(2);
            }
            __hip_atomic_store(&b->leafrel[g * 16], k, __ATOMIC_RELAXED,
                               __HIP_MEMORY_SCOPE_AGENT);
        } else {
            while (__hip_atomic_load(&b->leafrel[g * 16], __ATOMIC_RELAXED,
                                     __HIP_MEMORY_SCOPE_AGENT) < k)
                __builtin_amdgcn_s_sleep(2);
        }
    }
    __syncthreads();
}

// ---------------- phases ----------------

// Phase 1 (fused): zero deg/h1 + out=b2 (CP vec stores) AND central-dst edge
// scan (LDS central bitmap from ptr) -> list2; srcs (+centrals) -> markbm.
__device__ void ph_zp1(const P& p, int* smem) {
    unsigned* cbm = (unsigned*)smem;
    int* lbuf = smem + LBUF_OFF;
    int* scnt = smem + SCNT_OFF;
    for (int t = threadIdx.x; t < 3136; t += blockDim.x) cbm[t] = 0u;
    if (threadIdx.x == 0) scnt[0] = 0;
    __syncthreads();
    if (threadIdx.x < N_GRAPHS) {
        int c = p.ptr[threadIdx.x];
        atomicOr(&cbm[c >> 5], 1u << (c & 31));
        if (blockIdx.x == 0)
            atomicOr(&p.markbm[c >> 5], 1u << (c & 31));
    }
    int gid = blockIdx.x * blockDim.x + threadIdx.x;
    int gst = gridDim.x * blockDim.x;
    uv4 z4 = {0u, 0u, 0u, 0u};
    for (int i = gid; i < N_NODES / 4; i += gst)
        cpstore4u((unsigned*)p.deg + i * 4, z4);
    for (int i = gid; i < (CAPS * HID_CH) / 4; i += gst)
        cpstore4f(p.h1 + i * 4, (fv4){0.f, 0.f, 0.f, 0.f});
    for (int i = gid; i < (N_GRAPHS * OUT_CH) / 4; i += gst) {
        int c = (i * 4) & 127;
        fv4 v = { p.b2[c], p.b2[c + 1], p.b2[c + 2], p.b2[c + 3] };
        cpstore4f(p.out + i * 4, v);
    }
    __syncthreads();
    if (threadIdx.x < SCAN_CHUNK / 4) {
        int e = blockIdx.x * SCAN_CHUNK + threadIdx.x * 4;
        if (e < N_EDGES) {
            iv4 d4 = *(const iv4*)(p.dst + e);
#pragma unroll
            for (int k = 0; k < 4; ++k) {
                int d = d4[k];
                if ((cbm[d >> 5] >> (d & 31)) & 1u) {
                    int s = p.src[e + k];
                    atomicOr(&p.markbm[s >> 5], 1u << (s & 31));
                    lbuf[atomicAdd(&scnt[0], 1)] = e + k;
                }
            }
        }
    }
    __syncthreads();
    if (threadIdx.x == 0) scnt[1] = atomicAdd(&p.cnt[2], scnt[0]);
    __syncthreads();
    for (int t = threadIdx.x; t < scnt[0]; t += blockDim.x) {
        int gi = scnt[1] + t;
        if (gi < CAP2) astore(&p.list2[gi], lbuf[t]);
    }
}

// Phase 2 (fused): snapshot markbm; compact marked -> slots; scan -> list1/ndbm.
__device__ void ph_np2(const P& p, int* smem) {
    unsigned* mbs = (unsigned*)smem;
    int* lbuf = smem + LBUF_OFF;
    int* scnt = smem + SCNT_OFF;
    if (threadIdx.x == 0) scnt[0] = 0;
    snap_bm(p.markbm, mbs);

    int gidx = blockIdx.x * blockDim.x + threadIdx.x;
    int lane = threadIdx.x & 63;
    if (blockIdx.x * (int)blockDim.x < BM_WORDS) {
        unsigned w = (gidx < BM_WORDS) ? mbs[gidx] : 0u;
        if (w) atomicOr(&p.ndbm[gidx], w);
        int c = __popc(w);
        int inc = c;
        for (int off = 1; off < 64; off <<= 1) {
            int t = __shfl_up(inc, off, 64);
            if (lane >= off) inc += t;
        }
        int total = __shfl(inc, 63, 64);
        if (total > 0) {
            int base = 0;
            if (lane == 63) base = atomicAdd(&p.cnt[0], total);
            base = __shfl(base, 63, 64);
            int slot = base + inc - c;
            unsigned ww = w;
            while (ww) {
                int b = __ffs(ww) - 1; ww &= ww - 1;
                int n = (gidx << 5) + b;
                if (slot < CAPS) { astore(&p.map1[n], slot); astore(&p.slotnode[slot], n); }
                else              astore(&p.map1[n], 0);
                ++slot;
            }
        }
    }

    if (threadIdx.x < SCAN_CHUNK / 4) {
        int e = blockIdx.x * SCAN_CHUNK + threadIdx.x * 4;
        if (e < N_EDGES) {
            iv4 d4 = *(const iv4*)(p.dst + e);
#pragma unroll
            for (int k = 0; k < 4; ++k) {
                int d = d4[k];
                if ((mbs[d >> 5] >> (d & 31)) & 1u) {
                    int s = p.src[e + k];
                    atomicOr(&p.ndbm[s >> 5], 1u << (s & 31));
                    lbuf[atomicAdd(&scnt[0], 1)] = e + k;
                }
            }
        }
    }
    __syncthreads();
    if (threadIdx.x == 0) scnt[1] = atomicAdd(&p.cnt[1], scnt[0]);
    __syncthreads();
    for (int t = threadIdx.x; t < scnt[0]; t += blockDim.x) {
        int gi = scnt[1] + t;
        if (gi < CAP1) astore(&p.list1[gi], lbuf[t]);
    }
}

// Phase 3: snapshot ndbm; degree count only for dst in needed set.
__device__ void ph_p3(const P& p, int* smem) {
    unsigned* nds = (unsigned*)smem;
    snap_bm(p.ndbm, nds);
    if (threadIdx.x < SCAN_CHUNK / 4) {
        int e = blockIdx.x * SCAN_CHUNK + threadIdx.x * 4;
        if (e < N_EDGES) {
            iv4 d4 = *(const iv4*)(p.dst + e);
#pragma unroll
            for (int k = 0; k < 4; ++k) {
                int d = d4[k];
                if ((nds[d >> 5] >> (d & 31)) & 1u) atomicAdd(&p.deg[d], 1u);
            }
        }
    }
}

// Phase 4: layer-1, BATCHED metadata gather. Lane k (k<16) owns item
// wid + k*nw, so all CP metadata loads for the wave's <=9 items issue in
// ~3 parallel rounds instead of per-item serial chains. x rows prefetch
// 4 items per round. h1 accumulation stays atomicAdd.
__device__ void ph_l1(const P& p, int* smem) {
    float* w1s = (float*)smem;              // 1024 floats
    float* b1s = (float*)smem + 1024;       // 64 floats
    for (int t = threadIdx.x; t < IN_CH * HID_CH; t += blockDim.x) w1s[t] = p.W1[t];
    if (threadIdx.x < HID_CH) b1s[threadIdx.x] = p.b1[threadIdx.x];
    __syncthreads();
    int lane = threadIdx.x & 63;
    int wid = blockIdx.x * (blockDim.x >> 6) + (threadIdx.x >> 6);
    int nw = gridDim.x * (blockDim.x >> 6);
    int n1 = min(aload(&p.cnt[1]), CAP1);
    int nS = min(aload(&p.cnt[0]), CAPS);
    int tot = n1 + nS;                      // <= 69632 < 16*nw
    int nit = (tot - wid + nw - 1) / nw;    // items this wave owns (<=9)
    if (nit <= 0) return;

    // lane-parallel metadata gather (lanes 0..nit-1)
    int myw = wid + lane * nw;
    bool has = (lane < 16) && (myw < tot);
    int nsrc = 0, slot = 0; float isself = 0.0f, sc = 0.0f;
    if (has) {
        if (myw < n1) {
            int e = aload(&p.list1[myw]);
            int s = p.src[e];
            int d = p.dst[e];
            int sl = aload(&p.map1[d]); if (sl < 0) sl = 0;
            slot = sl; nsrc = s;
            float rs = rsqrtf((float)(1u + auload(&p.deg[s])));
            float rd = rsqrtf((float)(1u + auload(&p.deg[d])));
            sc = rs * rd;
        } else {
            slot = myw - n1;
            nsrc = aload(&p.slotnode[slot]);
            float r = rsqrtf((float)(1u + auload(&p.deg[nsrc])));
            sc = r * r; isself = 1.0f;
        }
    }

    for (int i0 = 0; i0 < nit; i0 += 4) {
        int cnt4 = min(4, nit - i0);
        int j = lane >> 4;                  // 0..3: which item this lane prefetches
        float xq = 0.0f;
        if (j < cnt4) {
            int nj = __shfl(nsrc, i0 + j, 64);
            xq = p.x[(size_t)nj * IN_CH + (lane & 15)];
        }
        for (int jj = 0; jj < cnt4; ++jj) {
            int it = i0 + jj;
            int slot_j  = __shfl(slot, it, 64);
            float sc_j  = __shfl(sc, it, 64);
            float self_j = __shfl(isself, it, 64);
            float t = 0.0f;
#pragma unroll
            for (int c = 0; c < IN_CH; ++c)
                t += __shfl(xq, jj * 16 + c, 64) * w1s[c * HID_CH + lane];
            atomicAdd(&p.h1[(size_t)slot_j * HID_CH + lane],
                      t * sc_j + self_j * b1s[lane]);
        }
    }
}

// Phase 5: layer-2. Items = list2 edges (ballot row resolution; duplicate rows
// each accumulate) + 128 self items. relu(h1) on read; atomics into out.
__device__ void ph_l2(const P& p, int* smem) {
    int* cent = smem;
    if (threadIdx.x < 128) cent[threadIdx.x] = p.ptr[threadIdx.x];
    __syncthreads();
    int lane = threadIdx.x & 63;
    int c0 = cent[lane];
    int c1v = cent[lane + 64];
    int wid = blockIdx.x * (blockDim.x >> 6) + (threadIdx.x >> 6);
    int nw = gridDim.x * (blockDim.x >> 6);
    int n2 = min(aload(&p.cnt[2]), CAP2);
    for (int w = wid; w < n2 + N_GRAPHS; w += nw) {
        int s, d, selfrow = -1;
        if (w < n2) {
            int e = aload(&p.list2[w]);
            s = p.src[e]; d = p.dst[e];
        } else {
            selfrow = w - n2;
            s = cent[selfrow]; d = s;
        }
        int slot = aload(&p.map1[s]); if (slot < 0) slot = 0;
        float rs = rsqrtf((float)(1u + auload(&p.deg[s])));
        float rd = rsqrtf((float)(1u + auload(&p.deg[d])));
        float norm = rs * rd;
        float myh = fmaxf(afload(&p.h1[(size_t)slot * HID_CH + lane]), 0.0f);
        float a0 = 0.0f, a1 = 0.0f;
#pragma unroll 8
        for (int j = 0; j < HID_CH; ++j) {
            float hv = __shfl(myh, j, 64);
            a0 += hv * p.W2[j * OUT_CH + lane];
            a1 += hv * p.W2[j * OUT_CH + lane + 64];
        }
        a0 *= norm; a1 *= norm;
        if (selfrow >= 0) {
            atomicAdd(&p.out[selfrow * OUT_CH + lane], a0);
            atomicAdd(&p.out[selfrow * OUT_CH + lane + 64], a1);
        } else {
            unsigned long long b0 = __ballot(c0 == d);
            unsigned long long b1 = __ballot(c1v == d);
            while (b0) {
                int r = __ffsll((long long)b0) - 1; b0 &= b0 - 1;
                atomicAdd(&p.out[r * OUT_CH + lane], a0);
                atomicAdd(&p.out[r * OUT_CH + lane + 64], a1);
            }
            while (b1) {
                int r = __ffsll((long long)b1) - 1 + 64; b1 &= b1 - 1;
                atomicAdd(&p.out[r * OUT_CH + lane], a0);
                atomicAdd(&p.out[r * OUT_CH + lane + 64], a1);
            }
        }
    }
}

// ---------------- kernels ----------------

__global__ void k_prep(P p) {
    int i = blockIdx.x * blockDim.x + threadIdx.x;
    int st = gridDim.x * blockDim.x;
    uv4 z4 = {0u, 0u, 0u, 0u};
    for (int n = i; n < BM_PAD / 4; n += st) {
        cpstore4u(p.markbm + n * 4, z4);
        cpstore4u(p.ndbm + n * 4, z4);
    }
    for (int n = i; n < BAR_INTS; n += st) astore(((int*)p.bar) + n, 0);
    if (i < 16) astore(&p.cnt[i], 0);
}

// Coop variant kept for the next round's switch-back (not launched this round).
__global__ void __launch_bounds__(256) k_mega(P p) {
    __shared__ int smem[SMEM_INTS];
    ph_zp1(p, smem);  gbar(p.bar, 1);
    ph_np2(p, smem);  gbar(p.bar, 2);
    ph_p3(p, smem);   gbar(p.bar, 3);
    ph_l1(p, smem);   gbar(p.bar, 4);
    ph_l2(p, smem);
}

// Standalone phase kernels — THIS round's path (per-phase rocprof rows).
__global__ void __launch_bounds__(256) k_zp1(P p) { __shared__ int s[SMEM_INTS]; ph_zp1(p, s); }
__global__ void __launch_bounds__(256) k_np2(P p) { __shared__ int s[SMEM_INTS]; ph_np2(p, s); }
__global__ void __launch_bounds__(256) k_p3(P p)  { __shared__ int s[SMEM_INTS]; ph_p3(p, s); }
__global__ void __launch_bounds__(256) k_l1(P p)  { __shared__ int s[SMEM_INTS]; ph_l1(p, s); }
__global__ void __launch_bounds__(256) k_l2(P p)  { __shared__ int s[SMEM_INTS]; ph_l2(p, s); }

// ---------------- launch ----------------

extern "C" void kernel_launch(void* const* d_in, const int* in_sizes, int n_in,
                              void* d_out, int out_size, void* d_ws, size_t ws_size,
                              hipStream_t stream) {
    P p;
    p.x   = (const float*)d_in[0];          // fp32 (validated)
    const int* edge = (const int*)d_in[1];  // int32 (validated)
    p.src = edge;
    p.dst = edge + N_EDGES;
    p.ptr = (const int*)d_in[2];
    p.W1  = (const float*)d_in[3];
    p.b1  = (const float*)d_in[4];
    p.W2  = (const float*)d_in[5];
    p.b2  = (const float*)d_in[6];
    p.out = (float*)d_out;

    char* q = (char*)d_ws;
    auto alloc = [&](size_t bytes) {
        char* r = q; q += (bytes + 255) & ~size_t(255); return r;
    };
    p.deg      = (unsigned*)alloc((size_t)N_NODES * 4);
    p.map1     = (int*)     alloc((size_t)N_NODES * 4);
    p.slotnode = (int*)     alloc((size_t)CAPS * 4);
    p.list1    = (int*)     alloc((size_t)CAP1 * 4);
    p.list2    = (int*)     alloc((size_t)CAP2 * 4);
    p.h1       = (float*)   alloc((size_t)CAPS * HID_CH * 4);
    p.markbm   = (unsigned*)alloc((size_t)BM_PAD * 4);
    p.ndbm     = (unsigned*)alloc((size_t)BM_PAD * 4);
    p.cnt      = (int*)     alloc(256);
    p.bar      = (GBar*)    alloc(sizeof(GBar));

    // DIAGNOSTIC ROUND: force the multi-kernel path (kernel boundaries = sync)
    // so rocprof exposes per-phase durations. k_mega/gbar retained for the
    // switch-back once the hot phase is identified.
    hipLaunchKernelGGL(k_prep, dim3(8),    dim3(256), 0, stream, p);
    hipLaunchKernelGGL(k_zp1,  dim3(NBLK), dim3(256), 0, stream, p);
    hipLaunchKernelGGL(k_np2,  dim3(NBLK), dim3(256), 0, stream, p);
    hipLaunchKernelGGL(k_p3,   dim3(NBLK), dim3(256), 0, stream, p);
    hipLaunchKernelGGL(k_l1,   dim3(NBLK), dim3(256), 0, stream, p);
    hipLaunchKernelGGL(k_l2,   dim3(NBLK), dim3(256), 0, stream, p);
}

// Round 17
// 106.725 us; speedup vs baseline: 14.2275x; 1.0248x over previous
//
#include <hip/hip_runtime.h>

// Problem constants (fixed by the reference)
#define N_NODES   100000
#define N_EDGES   1600000
#define IN_CH     16
#define HID_CH    64
#define OUT_CH    128
#define N_GRAPHS  128

// Capacities. Expected: slots ~2.2K, list1 ~35K, list2 ~2K.
#define CAPS  4096
#define CAP1  65536
#define CAP2  16384

#define BM_WORDS ((N_NODES + 31) / 32)      // 3125 words; snapshot 3136, alloc 3200
#define BM_PAD   3200

#define NBLK   2048                         // 8 blocks/CU x 256 CU
#define SCAN_CHUNK 784                      // 4-aligned; NBLK*784 >= N_EDGES

// LDS arena (ints): [0..3135] bitmap | w1s(1024)+b1s(64) | cent(128)
//                   lbuf @3136 (784) ; scnt @4000
#define SMEM_INTS 4224
#define LBUF_OFF  3136
#define SCNT_OFF  4000

typedef int      iv4 __attribute__((ext_vector_type(4)));
typedef float    fv4 __attribute__((ext_vector_type(4)));

struct P {
    const float* x; const int* src; const int* dst; const int* ptr;
    const float* W1; const float* b1; const float* W2; const float* b2;
    float* out;
    unsigned* deg; int* map1; int* slotnode; int* list1; int* list2;
    float* h1; unsigned* markbm; unsigned* ndbm; int* cnt;
};

// Snapshot bitmap global->LDS with ordinary cached int4 loads (L2-resident
// after the first block per XCD). Contiguous per-lane: conflict-free.
__device__ __forceinline__ void snap_bm(const unsigned* g, unsigned* lds) {
    for (int t = threadIdx.x; t < 3136 / 4; t += blockDim.x)
        ((iv4*)lds)[t] = ((const iv4*)g)[t];
    __syncthreads();
}

// ---------------- kernels ----------------
// Multi-kernel pipeline: dispatch boundaries provide cross-phase visibility
// (writeback at end, invalidate at start — validated R5-R9, absmax 0).
// Plain cached loads/stores everywhere; atomics only for true aggregation.

// Prep: zero deg/bitmaps/cnt, out = b2.
__global__ void k_prep(P p) {
    int i = blockIdx.x * blockDim.x + threadIdx.x;
    int st = gridDim.x * blockDim.x;
    iv4 z = {0, 0, 0, 0};
    for (int n = i; n < N_NODES / 4; n += st) ((iv4*)p.deg)[n] = z;
    for (int n = i; n < BM_PAD / 4; n += st) {
        ((iv4*)p.markbm)[n] = z;
        ((iv4*)p.ndbm)[n] = z;
    }
    for (int n = i; n < (N_GRAPHS * OUT_CH) / 4; n += st) {
        int c = (n * 4) & 127;
        ((fv4*)p.out)[n] = (fv4){ p.b2[c], p.b2[c + 1], p.b2[c + 2], p.b2[c + 3] };
    }
    if (i < 16) p.cnt[i] = 0;
}

// Pass 1: LDS central bitmap from ptr; scan chunk; central-dst edges -> list2
// (LDS buffer, one global counter atomic per block); srcs + centrals -> markbm.
__global__ void __launch_bounds__(256) k_p1(P p) {
    __shared__ int smem[SMEM_INTS];
    unsigned* cbm = (unsigned*)smem;
    int* lbuf = smem + LBUF_OFF;
    int* scnt = smem + SCNT_OFF;
    for (int t = threadIdx.x; t < 3136; t += blockDim.x) cbm[t] = 0u;
    if (threadIdx.x == 0) scnt[0] = 0;
    __syncthreads();
    if (threadIdx.x < N_GRAPHS) {
        int c = p.ptr[threadIdx.x];
        atomicOr(&cbm[c >> 5], 1u << (c & 31));
        if (blockIdx.x == 0)
            atomicOr(&p.markbm[c >> 5], 1u << (c & 31));
    }
    __syncthreads();
    if (threadIdx.x < SCAN_CHUNK / 4) {
        int e = blockIdx.x * SCAN_CHUNK + threadIdx.x * 4;
        if (e < N_EDGES) {
            iv4 d4 = *(const iv4*)(p.dst + e);
#pragma unroll
            for (int k = 0; k < 4; ++k) {
                int d = d4[k];
                if ((cbm[d >> 5] >> (d & 31)) & 1u) {
                    int s = p.src[e + k];
                    atomicOr(&p.markbm[s >> 5], 1u << (s & 31));
                    lbuf[atomicAdd(&scnt[0], 1)] = e + k;
                }
            }
        }
    }
    __syncthreads();
    if (threadIdx.x == 0) scnt[1] = atomicAdd(&p.cnt[2], scnt[0]);
    __syncthreads();
    for (int t = threadIdx.x; t < scnt[0]; t += blockDim.x) {
        int gi = scnt[1] + t;
        if (gi < CAP2) p.list2[gi] = lbuf[t];
    }
}

// Pass 2 (fused): snapshot markbm; (a) compact marked nodes -> slots
// (wave-aggregated counter; first 13 blocks cover all words); (b) scan:
// marked-dst edges -> list1 (LDS buffer), srcs -> ndbm.
__global__ void __launch_bounds__(256) k_np2(P p) {
    __shared__ int smem[SMEM_INTS];
    unsigned* mbs = (unsigned*)smem;
    int* lbuf = smem + LBUF_OFF;
    int* scnt = smem + SCNT_OFF;
    if (threadIdx.x == 0) scnt[0] = 0;
    snap_bm(p.markbm, mbs);                 // ends with __syncthreads

    // (a) node compaction
    int gidx = blockIdx.x * blockDim.x + threadIdx.x;
    int lane = threadIdx.x & 63;
    if (blockIdx.x * (int)blockDim.x < BM_WORDS) {
        unsigned w = (gidx < BM_WORDS) ? mbs[gidx] : 0u;
        if (w) atomicOr(&p.ndbm[gidx], w);
        int c = __popc(w);
        int inc = c;
        for (int off = 1; off < 64; off <<= 1) {
            int t = __shfl_up(inc, off, 64);
            if (lane >= off) inc += t;
        }
        int total = __shfl(inc, 63, 64);
        if (total > 0) {
            int base = 0;
            if (lane == 63) base = atomicAdd(&p.cnt[0], total);
            base = __shfl(base, 63, 64);
            int slot = base + inc - c;
            unsigned ww = w;
            while (ww) {
                int b = __ffs(ww) - 1; ww &= ww - 1;
                int n = (gidx << 5) + b;
                if (slot < CAPS) { p.map1[n] = slot; p.slotnode[slot] = n; }
                else               p.map1[n] = 0;   // overflow: clamp, never fault
                ++slot;
            }
        }
    }

    // (b) list1 scan
    if (threadIdx.x < SCAN_CHUNK / 4) {
        int e = blockIdx.x * SCAN_CHUNK + threadIdx.x * 4;
        if (e < N_EDGES) {
            iv4 d4 = *(const iv4*)(p.dst + e);
#pragma unroll
            for (int k = 0; k < 4; ++k) {
                int d = d4[k];
                if ((mbs[d >> 5] >> (d & 31)) & 1u) {
                    int s = p.src[e + k];
                    atomicOr(&p.ndbm[s >> 5], 1u << (s & 31));
                    lbuf[atomicAdd(&scnt[0], 1)] = e + k;
                }
            }
        }
    }
    __syncthreads();
    if (threadIdx.x == 0) scnt[1] = atomicAdd(&p.cnt[1], scnt[0]);
    __syncthreads();
    for (int t = threadIdx.x; t < scnt[0]; t += blockDim.x) {
        int gi = scnt[1] + t;
        if (gi < CAP1) p.list1[gi] = lbuf[t];
    }
}

// Pass 3: snapshot ndbm; zero the h1 rows that will be used; degree count
// only for dst in the needed set (~31% of edges).
__global__ void __launch_bounds__(256) k_p3(P p) {
    __shared__ int smem[SMEM_INTS];
    unsigned* nds = (unsigned*)smem;
    snap_bm(p.ndbm, nds);                   // ends with __syncthreads

    int nS = min(p.cnt[0], CAPS);           // final after k_np2
    int gid = blockIdx.x * blockDim.x + threadIdx.x;
    int gst = gridDim.x * blockDim.x;
    for (int i = gid; i < nS * (HID_CH / 4); i += gst)
        ((fv4*)p.h1)[i] = (fv4){0.f, 0.f, 0.f, 0.f};

    if (threadIdx.x < SCAN_CHUNK / 4) {
        int e = blockIdx.x * SCAN_CHUNK + threadIdx.x * 4;
        if (e < N_EDGES) {
            iv4 d4 = *(const iv4*)(p.dst + e);
#pragma unroll
            for (int k = 0; k < 4; ++k) {
                int d = d4[k];
                if ((nds[d >> 5] >> (d & 31)) & 1u) atomicAdd(&p.deg[d], 1u);
            }
        }
    }
}

// Layer-1: items = list1 edges + one self item per slot (bias folded; relu
// applied by l2 on read). Lane-parallel metadata gather (R16-validated),
// 4 x-rows prefetched per round. h1 accumulation via atomicAdd.
__global__ void __launch_bounds__(256) k_l1(P p) {
    __shared__ float w1s[IN_CH * HID_CH];
    __shared__ float b1s[HID_CH];
    for (int t = threadIdx.x; t < IN_CH * HID_CH; t += blockDim.x) w1s[t] = p.W1[t];
    if (threadIdx.x < HID_CH) b1s[threadIdx.x] = p.b1[threadIdx.x];
    __syncthreads();
    int lane = threadIdx.x & 63;
    int wid = blockIdx.x * (blockDim.x >> 6) + (threadIdx.x >> 6);
    int nw = gridDim.x * (blockDim.x >> 6);
    int n1 = min(p.cnt[1], CAP1);
    int nS = min(p.cnt[0], CAPS);
    int tot = n1 + nS;                      // <= 69632 < 16*nw
    int nit = (tot - wid + nw - 1) / nw;    // items this wave owns (<=9)
    if (nit <= 0) return;

    int myw = wid + lane * nw;
    bool has = (lane < 16) && (myw < tot);
    int nsrc = 0, slot = 0; float isself = 0.0f, sc = 0.0f;
    if (has) {
        if (myw < n1) {
            int e = p.list1[myw];
            int s = p.src[e];
            int d = p.dst[e];
            int sl = p.map1[d]; if (sl < 0) sl = 0;
            slot = sl; nsrc = s;
            float rs = rsqrtf((float)(1u + p.deg[s]));
            float rd = rsqrtf((float)(1u + p.deg[d]));
            sc = rs * rd;
        } else {
            slot = myw - n1;
            nsrc = p.slotnode[slot];
            float r = rsqrtf((float)(1u + p.deg[nsrc]));
            sc = r * r; isself = 1.0f;
        }
    }

    for (int i0 = 0; i0 < nit; i0 += 4) {
        int cnt4 = min(4, nit - i0);
        int j = lane >> 4;                  // 0..3: which item this lane prefetches
        float xq = 0.0f;
        if (j < cnt4) {
            int nj = __shfl(nsrc, i0 + j, 64);
            xq = p.x[(size_t)nj * IN_CH + (lane & 15)];
        }
        for (int jj = 0; jj < cnt4; ++jj) {
            int it = i0 + jj;
            int slot_j   = __shfl(slot, it, 64);
            float sc_j   = __shfl(sc, it, 64);
            float self_j = __shfl(isself, it, 64);
            float t = 0.0f;
#pragma unroll
            for (int c = 0; c < IN_CH; ++c)
                t += __shfl(xq, jj * 16 + c, 64) * w1s[c * HID_CH + lane];
            atomicAdd(&p.h1[(size_t)slot_j * HID_CH + lane],
                      t * sc_j + self_j * b1s[lane]);
        }
    }
}

// Layer-2: items = list2 edges (ballot row resolution; duplicate rows each
// accumulate independently) + 128 self items. relu(h1) on read; atomics
// straight into out (bias pre-set by k_prep).
__global__ void __launch_bounds__(256) k_l2(P p) {
    __shared__ int cent[128];
    if (threadIdx.x < 128) cent[threadIdx.x] = p.ptr[threadIdx.x];
    __syncthreads();
    int lane = threadIdx.x & 63;
    int c0 = cent[lane];
    int c1v = cent[lane + 64];
    int wid = blockIdx.x * (blockDim.x >> 6) + (threadIdx.x >> 6);
    int nw = gridDim.x * (blockDim.x >> 6);
    int n2 = min(p.cnt[2], CAP2);
    for (int w = wid; w < n2 + N_GRAPHS; w += nw) {
        int s, d, selfrow = -1;
        if (w < n2) {
            int e = p.list2[w];
            s = p.src[e]; d = p.dst[e];
        } else {
            selfrow = w - n2;
            s = cent[selfrow]; d = s;
        }
        int slot = p.map1[s]; if (slot < 0) slot = 0;  // always marked
        float rs = rsqrtf((float)(1u + p.deg[s]));
        float rd = rsqrtf((float)(1u + p.deg[d]));
        float norm = rs * rd;
        float myh = fmaxf(p.h1[(size_t)slot * HID_CH + lane], 0.0f);
        float a0 = 0.0f, a1 = 0.0f;
#pragma unroll 8
        for (int j = 0; j < HID_CH; ++j) {
            float hv = __shfl(myh, j, 64);
            a0 += hv * p.W2[j * OUT_CH + lane];
            a1 += hv * p.W2[j * OUT_CH + lane + 64];
        }
        a0 *= norm; a1 *= norm;
        if (selfrow >= 0) {
            atomicAdd(&p.out[selfrow * OUT_CH + lane], a0);
            atomicAdd(&p.out[selfrow * OUT_CH + lane + 64], a1);
        } else {
            unsigned long long b0 = __ballot(c0 == d);
            unsigned long long b1 = __ballot(c1v == d);
            while (b0) {
                int r = __ffsll((long long)b0) - 1; b0 &= b0 - 1;
                atomicAdd(&p.out[r * OUT_CH + lane], a0);
                atomicAdd(&p.out[r * OUT_CH + lane + 64], a1);
            }
            while (b1) {
                int r = __ffsll((long long)b1) - 1 + 64; b1 &= b1 - 1;
                atomicAdd(&p.out[r * OUT_CH + lane], a0);
                atomicAdd(&p.out[r * OUT_CH + lane + 64], a1);
            }
        }
    }
}

// ---------------- launch ----------------

extern "C" void kernel_launch(void* const* d_in, const int* in_sizes, int n_in,
                              void* d_out, int out_size, void* d_ws, size_t ws_size,
                              hipStream_t stream) {
    P p;
    p.x   = (const float*)d_in[0];          // fp32 (validated)
    const int* edge = (const int*)d_in[1];  // int32 (validated)
    p.src = edge;
    p.dst = edge + N_EDGES;
    p.ptr = (const int*)d_in[2];
    p.W1  = (const float*)d_in[3];
    p.b1  = (const float*)d_in[4];
    p.W2  = (const float*)d_in[5];
    p.b2  = (const float*)d_in[6];
    p.out = (float*)d_out;

    char* q = (char*)d_ws;
    auto alloc = [&](size_t bytes) {
        char* r = q; q += (bytes + 255) & ~size_t(255); return r;
    };
    p.deg      = (unsigned*)alloc((size_t)N_NODES * 4);
    p.map1     = (int*)     alloc((size_t)N_NODES * 4);
    p.slotnode = (int*)     alloc((size_t)CAPS * 4);
    p.list1    = (int*)     alloc((size_t)CAP1 * 4);
    p.list2    = (int*)     alloc((size_t)CAP2 * 4);
    p.h1       = (float*)   alloc((size_t)CAPS * HID_CH * 4);
    p.markbm   = (unsigned*)alloc((size_t)BM_PAD * 4);
    p.ndbm     = (unsigned*)alloc((size_t)BM_PAD * 4);
    p.cnt      = (int*)     alloc(256);

    // Multi-kernel pipeline (R16 A/B winner): kernel boundaries are the sync.
    hipLaunchKernelGGL(k_prep, dim3(256),  dim3(256), 0, stream, p);
    hipLaunchKernelGGL(k_p1,   dim3(NBLK), dim3(256), 0, stream, p);
    hipLaunchKernelGGL(k_np2,  dim3(NBLK), dim3(256), 0, stream, p);
    hipLaunchKernelGGL(k_p3,   dim3(NBLK), dim3(256), 0, stream, p);
    hipLaunchKernelGGL(k_l1,   dim3(NBLK), dim3(256), 0, stream, p);
    hipLaunchKernelGGL(k_l2,   dim3(NBLK), dim3(256), 0, stream, p);
}